// Round 1
// baseline (740.090 us; speedup 1.0000x reference)
//
#include <hip/hip_runtime.h>
#include <hip/hip_bf16.h>
#include <math.h>

#define H 2048
#define IMOE 1408
#define NEXP 8
#define T_TOK 2048
#define ISH 2816
#define SCALEF 2.5f

#define NT_GU_R (IMOE / 64)   // 22
#define NT_GU_S (ISH / 64)    // 44
#define NT_DN   (H / 128)     // 16
#define GU_GRID (39 * NT_GU_R + 16 * NT_GU_S)  // 858 + 704 = 1562
#define DN_GRID (39 * NT_DN + 16 * NT_DN)      // 624 + 256 = 880

typedef __attribute__((ext_vector_type(8))) short short8;
typedef __attribute__((ext_vector_type(4))) short short4v;
typedef __attribute__((ext_vector_type(4))) float floatx4;

union U8 { short8 s; unsigned u[4]; };

__device__ inline float b2f(short v) {
    unsigned int u = ((unsigned int)(unsigned short)v) << 16;
    float f; __builtin_memcpy(&f, &u, 4); return f;
}
__device__ inline short f2b(float f) {
    __hip_bfloat16 h = __float2bfloat16(f);
    short s; __builtin_memcpy(&s, &h, 2); return s;
}
__device__ __forceinline__ unsigned pkbf16(float a, float b) {
    float2 t; t.x = a; t.y = b;
    __hip_bfloat162 h2 = __float22bfloat162_rn(t);
    unsigned u; __builtin_memcpy(&u, &h2, 4); return u;
}

// async 16B/lane global->LDS; LDS dest = wave-uniform base + lane*16
__device__ __forceinline__ void async16(const short* g, short* l) {
    __builtin_amdgcn_global_load_lds(
        (const __attribute__((address_space(1))) unsigned*)g,
        (__attribute__((address_space(3))) unsigned*)l, 16, 0, 0);
}

// Bijective XCD-aware remap (m204): hardware assigns blockIdx%8 -> XCD.
// Give each XCD a CONTIGUOUS chunk of work ids so blocks sharing a B strip
// (consecutive work ids, mt-minor) co-reside on one XCD's L2.
__device__ __forceinline__ int xcd_map(int orig, int nwg) {
    int q = nwg >> 3, r = nwg & 7;
    int x = orig & 7, s = orig >> 3;
    int base = (x < r) ? x * (q + 1) : r * (q + 1) + (x - r) * q;
    return base + s;
}

// ---------------- Router (fp32, matches reference exactly) ----------------
__global__ __launch_bounds__(256) void router_kernel(
    const float* __restrict__ x, const float* __restrict__ rw,
    const float* __restrict__ bias,
    int* __restrict__ cnt, int* __restrict__ tokList, int* __restrict__ slotList,
    float* __restrict__ pairW)
{
    const int wid  = (blockIdx.x * 256 + threadIdx.x) >> 6;
    const int lane = threadIdx.x & 63;
    if (wid >= T_TOK) return;
    const float* xr = x + (size_t)wid * H;

    float acc[NEXP];
#pragma unroll
    for (int e = 0; e < NEXP; ++e) acc[e] = 0.f;

#pragma unroll
    for (int c = 0; c < 8; ++c) {
        int idx = (c * 64 + lane) * 4;
        floatx4 xv = *(const floatx4*)(xr + idx);
#pragma unroll
        for (int e = 0; e < NEXP; ++e) {
            floatx4 wv = *(const floatx4*)(rw + e * H + idx);
            acc[e] += xv.x * wv.x + xv.y * wv.y + xv.z * wv.z + xv.w * wv.w;
        }
    }
#pragma unroll
    for (int e = 0; e < NEXP; ++e)
        for (int off = 32; off; off >>= 1)
            acc[e] += __shfl_xor(acc[e], off, 64);

    if (lane == 0) {
        float s[NEXP], sfc[NEXP];
#pragma unroll
        for (int e = 0; e < NEXP; ++e) {
            s[e]   = 1.0f / (1.0f + expf(-acc[e]));
            sfc[e] = s[e] + bias[e];
        }
        float gs[4];
#pragma unroll
        for (int g = 0; g < 4; ++g) gs[g] = sfc[2 * g] + sfc[2 * g + 1];
        int g1 = 0;
        for (int g = 1; g < 4; ++g) if (gs[g] > gs[g1]) g1 = g;
        int g2 = -1;
        for (int g = 0; g < 4; ++g) {
            if (g == g1) continue;
            if (g2 < 0 || gs[g] > gs[g2]) g2 = g;
        }
        float msk[NEXP];
#pragma unroll
        for (int e = 0; e < NEXP; ++e) {
            int g = e >> 1;
            msk[e] = (g == g1 || g == g2) ? sfc[e] : 0.0f;
        }
        int e1 = 0;
        for (int e = 1; e < NEXP; ++e) if (msk[e] > msk[e1]) e1 = e;
        int e2 = -1;
        for (int e = 0; e < NEXP; ++e) {
            if (e == e1) continue;
            if (e2 < 0 || msk[e] > msk[e2]) e2 = e;
        }
        float w1 = s[e1], w2 = s[e2];
        float inv = SCALEF / (w1 + w2 + 1e-20f);
        w1 *= inv; w2 *= inv;
        int p1 = atomicAdd(&cnt[e1], 1);
        tokList[e1 * T_TOK + p1]  = wid;
        slotList[e1 * T_TOK + p1] = 2 * wid;
        pairW[2 * wid] = w1;
        int p2 = atomicAdd(&cnt[e2], 1);
        tokList[e2 * T_TOK + p2]  = wid;
        slotList[e2 * T_TOK + p2] = 2 * wid + 1;
        pairW[2 * wid + 1] = w2;
    }
}

// ---------------- Plan: counts -> compact row bases + tile-item prefix tables ----------------
// meta[0..8]  : M per entry (entry 8 = shared, 2048)
// meta[9..17] : compact row base
// meta[20..29]: gate/up item starts (meta[20]=0 .. meta[29]=total)
// meta[32..41]: down item starts
__global__ void plan_kernel(const int* __restrict__ cnt, int* __restrict__ meta)
{
    if (blockIdx.x != 0 || threadIdx.x != 0) return;
    int base = 0, gu = 0, dn = 0;
    meta[20] = 0; meta[32] = 0;
    for (int e = 0; e < NEXP; ++e) {
        int M = cnt[e];
        meta[e] = M;
        meta[9 + e] = base;
        base += M;
        int MT = (M + 127) >> 7;
        gu += MT * NT_GU_R;
        dn += MT * NT_DN;
        meta[21 + e] = gu;
        meta[33 + e] = dn;
    }
    meta[8]  = T_TOK;   // shared M
    meta[17] = 0;       // shared base (separate buffer)
    meta[29] = gu + 16 * NT_GU_S;
    meta[41] = dn + 16 * NT_DN;
}

// ---------------- fp32 -> bf16 convert (x only) ----------------
__global__ __launch_bounds__(256) void convert_kernel(
    const float* __restrict__ src, short* __restrict__ dst, int n4)
{
    int idx = blockIdx.x * 256 + threadIdx.x;
    int stride = gridDim.x * 256;
    for (; idx < n4; idx += stride) {
        floatx4 v = *(const floatx4*)(src + (size_t)idx * 4);
        short4v o = { f2b(v.x), f2b(v.y), f2b(v.z), f2b(v.w) };
        *(short4v*)(dst + (size_t)idx * 4) = o;
    }
}

// ---------------- Fused gate+up grouped GEMM ----------------
// BM=128 (A rows, gathered bf16 x), BN=64 per matrix, BK=64, K=2048 fixed.
// B (fp32 weights) staged with in-kernel cvt. XOR-swizzled LDS rows.
// Epilogue: silu(g)*u -> compact hidden (bf16).
__global__ __launch_bounds__(256) void gu_gemm(
    const short* __restrict__ xb,
    const float* __restrict__ gw, const float* __restrict__ uw,
    const float* __restrict__ sgw, const float* __restrict__ suw,
    short* __restrict__ hiddenP, short* __restrict__ hiddenS,
    const int* __restrict__ tokList, const int* __restrict__ meta)
{
    const int total = meta[29];
    if (blockIdx.x >= total) return;
    const int idx = xcd_map(blockIdx.x, total);
    int e = 0;
    while (e < 8 && idx >= meta[21 + e]) ++e;

    int M, NT, Nout, rowBase;
    const float *b1, *b2;
    const int* gat;
    short* outP;
    if (e < 8) {
        M = meta[e]; NT = NT_GU_R; Nout = IMOE; rowBase = meta[9 + e];
        b1 = gw + (size_t)e * IMOE * H;
        b2 = uw + (size_t)e * IMOE * H;
        gat = tokList + e * T_TOK;
        outP = hiddenP;
    } else {
        M = T_TOK; NT = NT_GU_S; Nout = ISH; rowBase = 0;
        b1 = sgw; b2 = suw; gat = nullptr; outP = hiddenS;
    }
    const int MT = (M + 127) >> 7;
    const int local = idx - meta[20 + e];
    const int mt = local % MT;          // mt-minor: adjacent blocks share weight tile
    const int nt = local / MT;

    __shared__ short As[128 * 64];
    __shared__ short Bg[64 * 64];
    __shared__ short Bu[64 * 64];

    const int tid  = threadIdx.x;
    const int w    = tid >> 6;
    const int lane = tid & 63;
    const int quad = lane >> 4;
    const int l16  = lane & 15;
    const int wm = w >> 1, wn = w & 1;

    // A staging (async16, swizzled source chunk)
    const int r8 = lane >> 3;                 // row within 8-row group
    const int cs = (lane & 7) ^ r8;           // source chunk (phys chunk = lane&7)
    const short* aSrc[4];
    short* ldsA[4];
#pragma unroll
    for (int i = 0; i < 4; ++i) {
        int r = w * 32 + i * 8 + r8;
        int p = mt * 128 + r;
        int pos = p < M ? p : (M - 1);
        int arow = gat ? gat[pos] : pos;
        aSrc[i] = xb + (size_t)arow * H + cs * 8;
        ldsA[i] = As + (w * 32 + i * 8) * 64;
    }

    // B staging indices (fp32 -> bf16 cvt path)
    const int br = tid >> 2;                  // 0..63
    const int bj = tid & 3;                   // 16-float col group
    const int bs = br & 7;
    const float* b1p = b1 + (size_t)(nt * 64 + br) * H + bj * 16;
    const float* b2p = b2 + (size_t)(nt * 64 + br) * H + bj * 16;
    short* bgDst0 = Bg + br * 64 + (((2 * bj)    ) ^ bs) * 8;
    short* bgDst1 = Bg + br * 64 + (((2 * bj) + 1) ^ bs) * 8;
    short* buDst0 = Bu + br * 64 + (((2 * bj)    ) ^ bs) * 8;
    short* buDst1 = Bu + br * 64 + (((2 * bj) + 1) ^ bs) * 8;

    floatx4 accg[4][2] = {};
    floatx4 accu[4][2] = {};

    for (int k0 = 0; k0 < H; k0 += 64) {
#pragma unroll
        for (int i = 0; i < 4; ++i)
            async16(aSrc[i] + k0, ldsA[i]);
        {
            floatx4 v0 = ((const floatx4*)(b1p + k0))[0];
            floatx4 v1 = ((const floatx4*)(b1p + k0))[1];
            floatx4 v2 = ((const floatx4*)(b1p + k0))[2];
            floatx4 v3 = ((const floatx4*)(b1p + k0))[3];
            U8 lo, hi;
            lo.u[0] = pkbf16(v0.x, v0.y); lo.u[1] = pkbf16(v0.z, v0.w);
            lo.u[2] = pkbf16(v1.x, v1.y); lo.u[3] = pkbf16(v1.z, v1.w);
            hi.u[0] = pkbf16(v2.x, v2.y); hi.u[1] = pkbf16(v2.z, v2.w);
            hi.u[2] = pkbf16(v3.x, v3.y); hi.u[3] = pkbf16(v3.z, v3.w);
            *(short8*)bgDst0 = lo.s;
            *(short8*)bgDst1 = hi.s;
        }
        {
            floatx4 v0 = ((const floatx4*)(b2p + k0))[0];
            floatx4 v1 = ((const floatx4*)(b2p + k0))[1];
            floatx4 v2 = ((const floatx4*)(b2p + k0))[2];
            floatx4 v3 = ((const floatx4*)(b2p + k0))[3];
            U8 lo, hi;
            lo.u[0] = pkbf16(v0.x, v0.y); lo.u[1] = pkbf16(v0.z, v0.w);
            lo.u[2] = pkbf16(v1.x, v1.y); lo.u[3] = pkbf16(v1.z, v1.w);
            hi.u[0] = pkbf16(v2.x, v2.y); hi.u[1] = pkbf16(v2.z, v2.w);
            hi.u[2] = pkbf16(v3.x, v3.y); hi.u[3] = pkbf16(v3.z, v3.w);
            *(short8*)buDst0 = lo.s;
            *(short8*)buDst1 = hi.s;
        }
        __syncthreads();
        const int sw = l16 & 7;
        short8 af[4], bgf[2], buf[2];
#pragma unroll
        for (int kk2 = 0; kk2 < 2; ++kk2) {
            const int c = kk2 * 4 + quad;
#pragma unroll
            for (int m = 0; m < 4; ++m)
                af[m] = *(const short8*)(As + (wm * 64 + m * 16 + l16) * 64 + (c ^ sw) * 8);
#pragma unroll
            for (int n = 0; n < 2; ++n) {
                bgf[n] = *(const short8*)(Bg + (wn * 32 + n * 16 + l16) * 64 + (c ^ sw) * 8);
                buf[n] = *(const short8*)(Bu + (wn * 32 + n * 16 + l16) * 64 + (c ^ sw) * 8);
            }
#pragma unroll
            for (int m = 0; m < 4; ++m)
#pragma unroll
                for (int n = 0; n < 2; ++n) {
                    accg[m][n] = __builtin_amdgcn_mfma_f32_16x16x32_bf16(af[m], bgf[n], accg[m][n], 0, 0, 0);
                    accu[m][n] = __builtin_amdgcn_mfma_f32_16x16x32_bf16(af[m], buf[n], accu[m][n], 0, 0, 0);
                }
        }
        __syncthreads();
    }

    // epilogue: silu(g)*u -> compact hidden. C/D layout: col=l16, row=quad*4+rr
#pragma unroll
    for (int m = 0; m < 4; ++m) {
#pragma unroll
        for (int rr = 0; rr < 4; ++rr) {
            int lr = wm * 64 + m * 16 + quad * 4 + rr;
            int p = mt * 128 + lr;
            if (p >= M) continue;
            size_t rowoff = (size_t)(rowBase + p) * Nout + nt * 64 + wn * 32;
#pragma unroll
            for (int n = 0; n < 2; ++n) {
                float g = accg[m][n][rr];
                float u = accu[m][n][rr];
                outP[rowoff + n * 16 + l16] = f2b(g / (1.0f + __expf(-g)) * u);
            }
        }
    }
}

// ---------------- Down grouped GEMM ----------------
// BM=128 (compact hidden rows), BN=128, BK=64, K = 1408 (routed) / 2816 (shared).
__global__ __launch_bounds__(256) void dn_gemm(
    const short* __restrict__ hiddenP, const short* __restrict__ hiddenS,
    const float* __restrict__ dw, const float* __restrict__ sdw,
    short* __restrict__ outPairs, short* __restrict__ sharedOut,
    const int* __restrict__ slotList, const int* __restrict__ meta)
{
    const int total = meta[41];
    if (blockIdx.x >= total) return;
    const int idx = xcd_map(blockIdx.x, total);
    int e = 0;
    while (e < 8 && idx >= meta[33 + e]) ++e;

    int M, K, rowBase;
    const float* bp;
    const short* Abase;
    const int* scat;
    short* outP;
    if (e < 8) {
        M = meta[e]; K = IMOE; rowBase = meta[9 + e];
        bp = dw + (size_t)e * H * IMOE;
        Abase = hiddenP; scat = slotList + e * T_TOK; outP = outPairs;
    } else {
        M = T_TOK; K = ISH; rowBase = 0;
        bp = sdw; Abase = hiddenS; scat = nullptr; outP = sharedOut;
    }
    const int MT = (M + 127) >> 7;
    const int local = idx - meta[32 + e];
    const int mt = local % MT;
    const int nt = local / MT;

    __shared__ short As[128 * 64];
    __shared__ short Bs[128 * 64];

    const int tid  = threadIdx.x;
    const int w    = tid >> 6;
    const int lane = tid & 63;
    const int quad = lane >> 4;
    const int l16  = lane & 15;
    const int wm = w >> 1, wn = w & 1;

    const int r8 = lane >> 3;
    const int cs = (lane & 7) ^ r8;
    const short* aSrc[4];
    short* ldsA[4];
#pragma unroll
    for (int i = 0; i < 4; ++i) {
        int r = w * 32 + i * 8 + r8;
        int p = mt * 128 + r;
        int pos = p < M ? p : (M - 1);
        aSrc[i] = Abase + (size_t)(rowBase + pos) * K + cs * 8;
        ldsA[i] = As + (w * 32 + i * 8) * 64;
    }

    const int br = tid >> 1;                  // 0..127
    const int bh = tid & 1;                   // 32-float half
    const int bs = br & 7;
    const float* bpp = bp + (size_t)(nt * 128 + br) * K + bh * 32;
    short* bDst[4];
#pragma unroll
    for (int i = 0; i < 4; ++i)
        bDst[i] = Bs + br * 64 + ((bh * 4 + i) ^ bs) * 8;

    floatx4 acc[4][4] = {};

    const int kIters = K >> 6;
    for (int kt = 0; kt < kIters; ++kt) {
        const int k0 = kt << 6;
#pragma unroll
        for (int i = 0; i < 4; ++i)
            async16(aSrc[i] + k0, ldsA[i]);
#pragma unroll
        for (int i = 0; i < 4; ++i) {
            floatx4 v0 = ((const floatx4*)(bpp + k0))[2 * i];
            floatx4 v1 = ((const floatx4*)(bpp + k0))[2 * i + 1];
            U8 c;
            c.u[0] = pkbf16(v0.x, v0.y); c.u[1] = pkbf16(v0.z, v0.w);
            c.u[2] = pkbf16(v1.x, v1.y); c.u[3] = pkbf16(v1.z, v1.w);
            *(short8*)bDst[i] = c.s;
        }
        __syncthreads();
        const int sw = l16 & 7;
        short8 af[4], bf[4];
#pragma unroll
        for (int kk2 = 0; kk2 < 2; ++kk2) {
            const int c = kk2 * 4 + quad;
#pragma unroll
            for (int m = 0; m < 4; ++m)
                af[m] = *(const short8*)(As + (wm * 64 + m * 16 + l16) * 64 + (c ^ sw) * 8);
#pragma unroll
            for (int n = 0; n < 4; ++n)
                bf[n] = *(const short8*)(Bs + (wn * 64 + n * 16 + l16) * 64 + (c ^ sw) * 8);
#pragma unroll
            for (int m = 0; m < 4; ++m)
#pragma unroll
                for (int n = 0; n < 4; ++n)
                    acc[m][n] = __builtin_amdgcn_mfma_f32_16x16x32_bf16(af[m], bf[n], acc[m][n], 0, 0, 0);
        }
        __syncthreads();
    }

#pragma unroll
    for (int m = 0; m < 4; ++m) {
#pragma unroll
        for (int rr = 0; rr < 4; ++rr) {
            int lr = wm * 64 + m * 16 + quad * 4 + rr;
            int p = mt * 128 + lr;
            if (p >= M) continue;
            int crow = scat ? scat[p] : p;
            size_t rowoff = (size_t)crow * H + nt * 128 + wn * 64;
#pragma unroll
            for (int n = 0; n < 4; ++n)
                outP[rowoff + n * 16 + l16] = f2b(acc[m][n][rr]);
        }
    }
}

// ---------------- Combine ----------------
__global__ __launch_bounds__(256) void combine_kernel(
    const short* __restrict__ outPairs, const short* __restrict__ sharedOut,
    const float* __restrict__ pairW, float* __restrict__ out)
{
    size_t gi = ((size_t)blockIdx.x * 256 + threadIdx.x) * 8;
    int t = (int)(gi >> 11);
    int h = (int)(gi & (H - 1));
    float w0 = pairW[2 * t], w1 = pairW[2 * t + 1];
    short8 p0 = *(const short8*)(outPairs + (size_t)(2 * t) * H + h);
    short8 p1 = *(const short8*)(outPairs + (size_t)(2 * t + 1) * H + h);
    short8 sh = *(const short8*)(sharedOut + gi);
    floatx4 o0, o1;
#pragma unroll
    for (int j = 0; j < 4; ++j)
        o0[j] = w0 * b2f(p0[j]) + w1 * b2f(p1[j]) + b2f(sh[j]);
#pragma unroll
    for (int j = 0; j < 4; ++j)
        o1[j] = w0 * b2f(p0[4 + j]) + w1 * b2f(p1[4 + j]) + b2f(sh[4 + j]);
    *(floatx4*)(out + gi)     = o0;
    *(floatx4*)(out + gi + 4) = o1;
}

extern "C" void kernel_launch(void* const* d_in, const int* in_sizes, int n_in,
                              void* d_out, int out_size, void* d_ws, size_t ws_size,
                              hipStream_t stream)
{
    const float* x    = (const float*)d_in[0];
    const float* rw   = (const float*)d_in[1];
    const float* bias = (const float*)d_in[2];
    const float* gw   = (const float*)d_in[3];
    const float* uw   = (const float*)d_in[4];
    const float* dw   = (const float*)d_in[5];
    const float* sgw  = (const float*)d_in[6];
    const float* suw  = (const float*)d_in[7];
    const float* sdw  = (const float*)d_in[8];
    float* out = (float*)d_out;

    char* ws = (char*)d_ws;
    size_t off = 0;
    auto alloc = [&](size_t bytes) {
        off = (off + 255) & ~(size_t)255;
        void* p = ws + off;
        off += bytes;
        return p;
    };
    int*   cnt       = (int*)  alloc(NEXP * sizeof(int));
    int*   tokList   = (int*)  alloc((size_t)NEXP * T_TOK * sizeof(int));
    int*   slotList  = (int*)  alloc((size_t)NEXP * T_TOK * sizeof(int));
    float* pairW     = (float*)alloc((size_t)2 * T_TOK * sizeof(float));
    int*   meta      = (int*)  alloc(64 * sizeof(int));
    short* xb        = (short*)alloc((size_t)T_TOK * H * sizeof(short));
    short* hiddenP   = (short*)alloc((size_t)2 * T_TOK * IMOE * sizeof(short));  // compact, 4096 rows
    short* hiddenS   = (short*)alloc((size_t)T_TOK * ISH * sizeof(short));
    short* outPairs  = (short*)alloc((size_t)2 * T_TOK * H * sizeof(short));
    short* sharedOut = (short*)alloc((size_t)T_TOK * H * sizeof(short));
    (void)ws_size;

    hipMemsetAsync(cnt, 0, NEXP * sizeof(int), stream);

    router_kernel<<<T_TOK / 4, 256, 0, stream>>>(x, rw, bias, cnt, tokList, slotList, pairW);
    plan_kernel<<<1, 64, 0, stream>>>(cnt, meta);
    convert_kernel<<<2048, 256, 0, stream>>>(x, xb, T_TOK * H / 4);

    gu_gemm<<<GU_GRID, 256, 0, stream>>>(xb, gw, uw, sgw, suw,
                                         hiddenP, hiddenS, tokList, meta);
    dn_gemm<<<DN_GRID, 256, 0, stream>>>(hiddenP, hiddenS, dw, sdw,
                                         outPairs, sharedOut, slotList, meta);

    combine_kernel<<<(T_TOK * H / 8) / 256, 256, 0, stream>>>(outPairs, sharedOut, pairW, out);
}

// Round 2
// 687.499 us; speedup vs baseline: 1.0765x; 1.0765x over previous
//
#include <hip/hip_runtime.h>
#include <hip/hip_bf16.h>
#include <math.h>

#define H 2048
#define IMOE 1408
#define NEXP 8
#define T_TOK 2048
#define ISH 2816
#define SCALEF 2.5f

#define NT_GU_R (IMOE / 64)   // 22
#define NT_GU_S (ISH / 64)    // 44
#define NT_DN   (H / 128)     // 16
#define GU_GRID (39 * NT_GU_R + 16 * NT_GU_S)  // 858 + 704 = 1562
#define DN_GRID (39 * NT_DN + 16 * NT_DN)      // 624 + 256 = 880

typedef __attribute__((ext_vector_type(8))) short short8;
typedef __attribute__((ext_vector_type(4))) short short4v;
typedef __attribute__((ext_vector_type(4))) float floatx4;

union U8 { short8 s; unsigned u[4]; };

__device__ inline float b2f(short v) {
    unsigned int u = ((unsigned int)(unsigned short)v) << 16;
    float f; __builtin_memcpy(&f, &u, 4); return f;
}
__device__ inline short f2b(float f) {
    __hip_bfloat16 h = __float2bfloat16(f);
    short s; __builtin_memcpy(&s, &h, 2); return s;
}
__device__ __forceinline__ unsigned pkbf16(float a, float b) {
    float2 t; t.x = a; t.y = b;
    __hip_bfloat162 h2 = __float22bfloat162_rn(t);
    unsigned u; __builtin_memcpy(&u, &h2, 4); return u;
}

// async 16B/lane global->LDS; LDS dest = wave-uniform base + lane*16
__device__ __forceinline__ void async16(const short* g, short* l) {
    __builtin_amdgcn_global_load_lds(
        (const __attribute__((address_space(1))) unsigned*)g,
        (__attribute__((address_space(3))) unsigned*)l, 16, 0, 0);
}

// Bijective XCD-aware remap (m204): hardware assigns blockIdx%8 -> XCD.
// Give each XCD a CONTIGUOUS chunk of work ids so blocks sharing a B strip
// (consecutive work ids, mt-minor) co-reside on one XCD's L2.
__device__ __forceinline__ int xcd_map(int orig, int nwg) {
    int q = nwg >> 3, r = nwg & 7;
    int x = orig & 7, s = orig >> 3;
    int base = (x < r) ? x * (q + 1) : r * (q + 1) + (x - r) * q;
    return base + s;
}

// ---------------- Router (fp32, matches reference exactly) ----------------
__global__ __launch_bounds__(256) void router_kernel(
    const float* __restrict__ x, const float* __restrict__ rw,
    const float* __restrict__ bias,
    int* __restrict__ cnt, int* __restrict__ tokList, int* __restrict__ slotList,
    float* __restrict__ pairW)
{
    const int wid  = (blockIdx.x * 256 + threadIdx.x) >> 6;
    const int lane = threadIdx.x & 63;
    if (wid >= T_TOK) return;
    const float* xr = x + (size_t)wid * H;

    float acc[NEXP];
#pragma unroll
    for (int e = 0; e < NEXP; ++e) acc[e] = 0.f;

#pragma unroll
    for (int c = 0; c < 8; ++c) {
        int idx = (c * 64 + lane) * 4;
        floatx4 xv = *(const floatx4*)(xr + idx);
#pragma unroll
        for (int e = 0; e < NEXP; ++e) {
            floatx4 wv = *(const floatx4*)(rw + e * H + idx);
            acc[e] += xv.x * wv.x + xv.y * wv.y + xv.z * wv.z + xv.w * wv.w;
        }
    }
#pragma unroll
    for (int e = 0; e < NEXP; ++e)
        for (int off = 32; off; off >>= 1)
            acc[e] += __shfl_xor(acc[e], off, 64);

    if (lane == 0) {
        float s[NEXP], sfc[NEXP];
#pragma unroll
        for (int e = 0; e < NEXP; ++e) {
            s[e]   = 1.0f / (1.0f + expf(-acc[e]));
            sfc[e] = s[e] + bias[e];
        }
        float gs[4];
#pragma unroll
        for (int g = 0; g < 4; ++g) gs[g] = sfc[2 * g] + sfc[2 * g + 1];
        int g1 = 0;
        for (int g = 1; g < 4; ++g) if (gs[g] > gs[g1]) g1 = g;
        int g2 = -1;
        for (int g = 0; g < 4; ++g) {
            if (g == g1) continue;
            if (g2 < 0 || gs[g] > gs[g2]) g2 = g;
        }
        float msk[NEXP];
#pragma unroll
        for (int e = 0; e < NEXP; ++e) {
            int g = e >> 1;
            msk[e] = (g == g1 || g == g2) ? sfc[e] : 0.0f;
        }
        int e1 = 0;
        for (int e = 1; e < NEXP; ++e) if (msk[e] > msk[e1]) e1 = e;
        int e2 = -1;
        for (int e = 0; e < NEXP; ++e) {
            if (e == e1) continue;
            if (e2 < 0 || msk[e] > msk[e2]) e2 = e;
        }
        float w1 = s[e1], w2 = s[e2];
        float inv = SCALEF / (w1 + w2 + 1e-20f);
        w1 *= inv; w2 *= inv;
        int p1 = atomicAdd(&cnt[e1], 1);
        tokList[e1 * T_TOK + p1]  = wid;
        slotList[e1 * T_TOK + p1] = 2 * wid;
        pairW[2 * wid] = w1;
        int p2 = atomicAdd(&cnt[e2], 1);
        tokList[e2 * T_TOK + p2]  = wid;
        slotList[e2 * T_TOK + p2] = 2 * wid + 1;
        pairW[2 * wid + 1] = w2;
    }
}

// ---------------- Plan: counts -> compact row bases + tile-item prefix tables ----------------
// meta[0..8]  : M per entry (entry 8 = shared, 2048)
// meta[9..17] : compact row base
// meta[20..29]: gate/up item starts (meta[20]=0 .. meta[29]=total; meta[28]=routed end)
// meta[32..41]: down item starts (meta[40]=routed end)
__global__ void plan_kernel(const int* __restrict__ cnt, int* __restrict__ meta)
{
    if (blockIdx.x != 0 || threadIdx.x != 0) return;
    int base = 0, gu = 0, dn = 0;
    meta[20] = 0; meta[32] = 0;
    for (int e = 0; e < NEXP; ++e) {
        int M = cnt[e];
        meta[e] = M;
        meta[9 + e] = base;
        base += M;
        int MT = (M + 127) >> 7;
        gu += MT * NT_GU_R;
        dn += MT * NT_DN;
        meta[21 + e] = gu;
        meta[33 + e] = dn;
    }
    meta[8]  = T_TOK;   // shared M
    meta[17] = 0;       // shared base (separate buffer)
    meta[29] = gu + 16 * NT_GU_S;
    meta[41] = dn + 16 * NT_DN;
}

// ---------------- fp32 -> bf16 convert (x only) ----------------
__global__ __launch_bounds__(256) void convert_kernel(
    const float* __restrict__ src, short* __restrict__ dst, int n4)
{
    int idx = blockIdx.x * 256 + threadIdx.x;
    int stride = gridDim.x * 256;
    for (; idx < n4; idx += stride) {
        floatx4 v = *(const floatx4*)(src + (size_t)idx * 4);
        short4v o = { f2b(v.x), f2b(v.y), f2b(v.z), f2b(v.w) };
        *(short4v*)(dst + (size_t)idx * 4) = o;
    }
}

// ---------------- Fused gate+up grouped GEMM ----------------
// BM=128 (A rows, gathered bf16 x), BN=64 per matrix, BK=64, K=2048 fixed.
// B (fp32 weights) staged with in-kernel cvt. XOR-swizzled LDS rows.
// Epilogue: silu(g)*u -> compact hidden (bf16).
// Uniform work per id (K=2048 everywhere) -> single-range XCD remap is balanced.
__global__ __launch_bounds__(256) void gu_gemm(
    const short* __restrict__ xb,
    const float* __restrict__ gw, const float* __restrict__ uw,
    const float* __restrict__ sgw, const float* __restrict__ suw,
    short* __restrict__ hiddenP, short* __restrict__ hiddenS,
    const int* __restrict__ tokList, const int* __restrict__ meta)
{
    const int total = meta[29];
    if (blockIdx.x >= total) return;
    const int idx = xcd_map(blockIdx.x, total);
    int e = 0;
    while (e < 8 && idx >= meta[21 + e]) ++e;

    int M, NT, Nout, rowBase;
    const float *b1, *b2;
    const int* gat;
    short* outP;
    if (e < 8) {
        M = meta[e]; NT = NT_GU_R; Nout = IMOE; rowBase = meta[9 + e];
        b1 = gw + (size_t)e * IMOE * H;
        b2 = uw + (size_t)e * IMOE * H;
        gat = tokList + e * T_TOK;
        outP = hiddenP;
    } else {
        M = T_TOK; NT = NT_GU_S; Nout = ISH; rowBase = 0;
        b1 = sgw; b2 = suw; gat = nullptr; outP = hiddenS;
    }
    const int MT = (M + 127) >> 7;
    const int local = idx - meta[20 + e];
    const int mt = local % MT;          // mt-minor: adjacent blocks share weight tile
    const int nt = local / MT;

    __shared__ short As[128 * 64];
    __shared__ short Bg[64 * 64];
    __shared__ short Bu[64 * 64];

    const int tid  = threadIdx.x;
    const int w    = tid >> 6;
    const int lane = tid & 63;
    const int quad = lane >> 4;
    const int l16  = lane & 15;
    const int wm = w >> 1, wn = w & 1;

    // A staging (async16, swizzled source chunk)
    const int r8 = lane >> 3;                 // row within 8-row group
    const int cs = (lane & 7) ^ r8;           // source chunk (phys chunk = lane&7)
    const short* aSrc[4];
    short* ldsA[4];
#pragma unroll
    for (int i = 0; i < 4; ++i) {
        int r = w * 32 + i * 8 + r8;
        int p = mt * 128 + r;
        int pos = p < M ? p : (M - 1);
        int arow = gat ? gat[pos] : pos;
        aSrc[i] = xb + (size_t)arow * H + cs * 8;
        ldsA[i] = As + (w * 32 + i * 8) * 64;
    }

    // B staging indices (fp32 -> bf16 cvt path)
    const int br = tid >> 2;                  // 0..63
    const int bj = tid & 3;                   // 16-float col group
    const int bs = br & 7;
    const float* b1p = b1 + (size_t)(nt * 64 + br) * H + bj * 16;
    const float* b2p = b2 + (size_t)(nt * 64 + br) * H + bj * 16;
    short* bgDst0 = Bg + br * 64 + (((2 * bj)    ) ^ bs) * 8;
    short* bgDst1 = Bg + br * 64 + (((2 * bj) + 1) ^ bs) * 8;
    short* buDst0 = Bu + br * 64 + (((2 * bj)    ) ^ bs) * 8;
    short* buDst1 = Bu + br * 64 + (((2 * bj) + 1) ^ bs) * 8;

    floatx4 accg[4][2] = {};
    floatx4 accu[4][2] = {};

    for (int k0 = 0; k0 < H; k0 += 64) {
#pragma unroll
        for (int i = 0; i < 4; ++i)
            async16(aSrc[i] + k0, ldsA[i]);
        {
            floatx4 v0 = ((const floatx4*)(b1p + k0))[0];
            floatx4 v1 = ((const floatx4*)(b1p + k0))[1];
            floatx4 v2 = ((const floatx4*)(b1p + k0))[2];
            floatx4 v3 = ((const floatx4*)(b1p + k0))[3];
            U8 lo, hi;
            lo.u[0] = pkbf16(v0.x, v0.y); lo.u[1] = pkbf16(v0.z, v0.w);
            lo.u[2] = pkbf16(v1.x, v1.y); lo.u[3] = pkbf16(v1.z, v1.w);
            hi.u[0] = pkbf16(v2.x, v2.y); hi.u[1] = pkbf16(v2.z, v2.w);
            hi.u[2] = pkbf16(v3.x, v3.y); hi.u[3] = pkbf16(v3.z, v3.w);
            *(short8*)bgDst0 = lo.s;
            *(short8*)bgDst1 = hi.s;
        }
        {
            floatx4 v0 = ((const floatx4*)(b2p + k0))[0];
            floatx4 v1 = ((const floatx4*)(b2p + k0))[1];
            floatx4 v2 = ((const floatx4*)(b2p + k0))[2];
            floatx4 v3 = ((const floatx4*)(b2p + k0))[3];
            U8 lo, hi;
            lo.u[0] = pkbf16(v0.x, v0.y); lo.u[1] = pkbf16(v0.z, v0.w);
            lo.u[2] = pkbf16(v1.x, v1.y); lo.u[3] = pkbf16(v1.z, v1.w);
            hi.u[0] = pkbf16(v2.x, v2.y); hi.u[1] = pkbf16(v2.z, v2.w);
            hi.u[2] = pkbf16(v3.x, v3.y); hi.u[3] = pkbf16(v3.z, v3.w);
            *(short8*)buDst0 = lo.s;
            *(short8*)buDst1 = hi.s;
        }
        __syncthreads();
        const int sw = l16 & 7;
        short8 af[4], bgf[2], buf[2];
#pragma unroll
        for (int kk2 = 0; kk2 < 2; ++kk2) {
            const int c = kk2 * 4 + quad;
#pragma unroll
            for (int m = 0; m < 4; ++m)
                af[m] = *(const short8*)(As + (wm * 64 + m * 16 + l16) * 64 + (c ^ sw) * 8);
#pragma unroll
            for (int n = 0; n < 2; ++n) {
                bgf[n] = *(const short8*)(Bg + (wn * 32 + n * 16 + l16) * 64 + (c ^ sw) * 8);
                buf[n] = *(const short8*)(Bu + (wn * 32 + n * 16 + l16) * 64 + (c ^ sw) * 8);
            }
#pragma unroll
            for (int m = 0; m < 4; ++m)
#pragma unroll
                for (int n = 0; n < 2; ++n) {
                    accg[m][n] = __builtin_amdgcn_mfma_f32_16x16x32_bf16(af[m], bgf[n], accg[m][n], 0, 0, 0);
                    accu[m][n] = __builtin_amdgcn_mfma_f32_16x16x32_bf16(af[m], buf[n], accu[m][n], 0, 0, 0);
                }
        }
        __syncthreads();
    }

    // epilogue: silu(g)*u -> compact hidden. C/D layout: col=l16, row=quad*4+rr
#pragma unroll
    for (int m = 0; m < 4; ++m) {
#pragma unroll
        for (int rr = 0; rr < 4; ++rr) {
            int lr = wm * 64 + m * 16 + quad * 4 + rr;
            int p = mt * 128 + lr;
            if (p >= M) continue;
            size_t rowoff = (size_t)(rowBase + p) * Nout + nt * 64 + wn * 32;
#pragma unroll
            for (int n = 0; n < 2; ++n) {
                float g = accg[m][n][rr];
                float u = accu[m][n][rr];
                outP[rowoff + n * 16 + l16] = f2b(g / (1.0f + __expf(-g)) * u);
            }
        }
    }
}

// ---------------- Down grouped GEMM ----------------
// BM=128 (compact hidden rows), BN=128, BK=64, K = 1408 (routed) / 2816 (shared).
// NON-uniform work per id: shared tiles have 2x the K-loop. A single-range
// XCD remap piles all K=2816 tiles onto the last ~2.3 XCDs -> 1.5x makespan
// (measured: round-1 regression 277us, Occ 14%). Fix: remap routed and shared
// ranges INDEPENDENTLY so every XCD gets a balanced mix while keeping
// contiguous-chunk L2 locality within each range.
__global__ __launch_bounds__(256) void dn_gemm(
    const short* __restrict__ hiddenP, const short* __restrict__ hiddenS,
    const float* __restrict__ dw, const float* __restrict__ sdw,
    short* __restrict__ outPairs, short* __restrict__ sharedOut,
    const int* __restrict__ slotList, const int* __restrict__ meta)
{
    const int total = meta[41];
    if (blockIdx.x >= total) return;
    const int rtot = meta[40];   // routed id count (K=1408 tiles)
    int idx;
    if (blockIdx.x < rtot) idx = xcd_map(blockIdx.x, rtot);
    else                   idx = rtot + xcd_map(blockIdx.x - rtot, total - rtot);
    int e = 0;
    while (e < 8 && idx >= meta[33 + e]) ++e;

    int M, K, rowBase;
    const float* bp;
    const short* Abase;
    const int* scat;
    short* outP;
    if (e < 8) {
        M = meta[e]; K = IMOE; rowBase = meta[9 + e];
        bp = dw + (size_t)e * H * IMOE;
        Abase = hiddenP; scat = slotList + e * T_TOK; outP = outPairs;
    } else {
        M = T_TOK; K = ISH; rowBase = 0;
        bp = sdw; Abase = hiddenS; scat = nullptr; outP = sharedOut;
    }
    const int MT = (M + 127) >> 7;
    const int local = idx - meta[32 + e];
    const int mt = local % MT;
    const int nt = local / MT;

    __shared__ short As[128 * 64];
    __shared__ short Bs[128 * 64];

    const int tid  = threadIdx.x;
    const int w    = tid >> 6;
    const int lane = tid & 63;
    const int quad = lane >> 4;
    const int l16  = lane & 15;
    const int wm = w >> 1, wn = w & 1;

    const int r8 = lane >> 3;
    const int cs = (lane & 7) ^ r8;
    const short* aSrc[4];
    short* ldsA[4];
#pragma unroll
    for (int i = 0; i < 4; ++i) {
        int r = w * 32 + i * 8 + r8;
        int p = mt * 128 + r;
        int pos = p < M ? p : (M - 1);
        aSrc[i] = Abase + (size_t)(rowBase + pos) * K + cs * 8;
        ldsA[i] = As + (w * 32 + i * 8) * 64;
    }

    const int br = tid >> 1;                  // 0..127
    const int bh = tid & 1;                   // 32-float half
    const int bs = br & 7;
    const float* bpp = bp + (size_t)(nt * 128 + br) * K + bh * 32;
    short* bDst[4];
#pragma unroll
    for (int i = 0; i < 4; ++i)
        bDst[i] = Bs + br * 64 + ((bh * 4 + i) ^ bs) * 8;

    floatx4 acc[4][4] = {};

    const int kIters = K >> 6;
    for (int kt = 0; kt < kIters; ++kt) {
        const int k0 = kt << 6;
#pragma unroll
        for (int i = 0; i < 4; ++i)
            async16(aSrc[i] + k0, ldsA[i]);
#pragma unroll
        for (int i = 0; i < 4; ++i) {
            floatx4 v0 = ((const floatx4*)(bpp + k0))[2 * i];
            floatx4 v1 = ((const floatx4*)(bpp + k0))[2 * i + 1];
            U8 c;
            c.u[0] = pkbf16(v0.x, v0.y); c.u[1] = pkbf16(v0.z, v0.w);
            c.u[2] = pkbf16(v1.x, v1.y); c.u[3] = pkbf16(v1.z, v1.w);
            *(short8*)bDst[i] = c.s;
        }
        __syncthreads();
        const int sw = l16 & 7;
        short8 af[4], bf[4];
#pragma unroll
        for (int kk2 = 0; kk2 < 2; ++kk2) {
            const int c = kk2 * 4 + quad;
#pragma unroll
            for (int m = 0; m < 4; ++m)
                af[m] = *(const short8*)(As + (wm * 64 + m * 16 + l16) * 64 + (c ^ sw) * 8);
#pragma unroll
            for (int n = 0; n < 4; ++n)
                bf[n] = *(const short8*)(Bs + (wn * 64 + n * 16 + l16) * 64 + (c ^ sw) * 8);
#pragma unroll
            for (int m = 0; m < 4; ++m)
#pragma unroll
                for (int n = 0; n < 4; ++n)
                    acc[m][n] = __builtin_amdgcn_mfma_f32_16x16x32_bf16(af[m], bf[n], acc[m][n], 0, 0, 0);
        }
        __syncthreads();
    }

#pragma unroll
    for (int m = 0; m < 4; ++m) {
#pragma unroll
        for (int rr = 0; rr < 4; ++rr) {
            int lr = wm * 64 + m * 16 + quad * 4 + rr;
            int p = mt * 128 + lr;
            if (p >= M) continue;
            int crow = scat ? scat[p] : p;
            size_t rowoff = (size_t)crow * H + nt * 128 + wn * 64;
#pragma unroll
            for (int n = 0; n < 4; ++n)
                outP[rowoff + n * 16 + l16] = f2b(acc[m][n][rr]);
        }
    }
}

// ---------------- Combine ----------------
__global__ __launch_bounds__(256) void combine_kernel(
    const short* __restrict__ outPairs, const short* __restrict__ sharedOut,
    const float* __restrict__ pairW, float* __restrict__ out)
{
    size_t gi = ((size_t)blockIdx.x * 256 + threadIdx.x) * 8;
    int t = (int)(gi >> 11);
    int h = (int)(gi & (H - 1));
    float w0 = pairW[2 * t], w1 = pairW[2 * t + 1];
    short8 p0 = *(const short8*)(outPairs + (size_t)(2 * t) * H + h);
    short8 p1 = *(const short8*)(outPairs + (size_t)(2 * t + 1) * H + h);
    short8 sh = *(const short8*)(sharedOut + gi);
    floatx4 o0, o1;
#pragma unroll
    for (int j = 0; j < 4; ++j)
        o0[j] = w0 * b2f(p0[j]) + w1 * b2f(p1[j]) + b2f(sh[j]);
#pragma unroll
    for (int j = 0; j < 4; ++j)
        o1[j] = w0 * b2f(p0[4 + j]) + w1 * b2f(p1[4 + j]) + b2f(sh[4 + j]);
    *(floatx4*)(out + gi)     = o0;
    *(floatx4*)(out + gi + 4) = o1;
}

extern "C" void kernel_launch(void* const* d_in, const int* in_sizes, int n_in,
                              void* d_out, int out_size, void* d_ws, size_t ws_size,
                              hipStream_t stream)
{
    const float* x    = (const float*)d_in[0];
    const float* rw   = (const float*)d_in[1];
    const float* bias = (const float*)d_in[2];
    const float* gw   = (const float*)d_in[3];
    const float* uw   = (const float*)d_in[4];
    const float* dw   = (const float*)d_in[5];
    const float* sgw  = (const float*)d_in[6];
    const float* suw  = (const float*)d_in[7];
    const float* sdw  = (const float*)d_in[8];
    float* out = (float*)d_out;

    char* ws = (char*)d_ws;
    size_t off = 0;
    auto alloc = [&](size_t bytes) {
        off = (off + 255) & ~(size_t)255;
        void* p = ws + off;
        off += bytes;
        return p;
    };
    int*   cnt       = (int*)  alloc(NEXP * sizeof(int));
    int*   tokList   = (int*)  alloc((size_t)NEXP * T_TOK * sizeof(int));
    int*   slotList  = (int*)  alloc((size_t)NEXP * T_TOK * sizeof(int));
    float* pairW     = (float*)alloc((size_t)2 * T_TOK * sizeof(float));
    int*   meta      = (int*)  alloc(64 * sizeof(int));
    short* xb        = (short*)alloc((size_t)T_TOK * H * sizeof(short));
    short* hiddenP   = (short*)alloc((size_t)2 * T_TOK * IMOE * sizeof(short));  // compact, 4096 rows
    short* hiddenS   = (short*)alloc((size_t)T_TOK * ISH * sizeof(short));
    short* outPairs  = (short*)alloc((size_t)2 * T_TOK * H * sizeof(short));
    short* sharedOut = (short*)alloc((size_t)T_TOK * H * sizeof(short));
    (void)ws_size;

    hipMemsetAsync(cnt, 0, NEXP * sizeof(int), stream);

    router_kernel<<<T_TOK / 4, 256, 0, stream>>>(x, rw, bias, cnt, tokList, slotList, pairW);
    plan_kernel<<<1, 64, 0, stream>>>(cnt, meta);
    convert_kernel<<<2048, 256, 0, stream>>>(x, xb, T_TOK * H / 4);

    gu_gemm<<<GU_GRID, 256, 0, stream>>>(xb, gw, uw, sgw, suw,
                                         hiddenP, hiddenS, tokList, meta);
    dn_gemm<<<DN_GRID, 256, 0, stream>>>(hiddenP, hiddenS, dw, sdw,
                                         outPairs, sharedOut, slotList, meta);

    combine_kernel<<<(T_TOK * H / 8) / 256, 256, 0, stream>>>(outPairs, sharedOut, pairW, out);
}

// Round 3
// 657.590 us; speedup vs baseline: 1.1255x; 1.0455x over previous
//
#include <hip/hip_runtime.h>
#include <hip/hip_bf16.h>
#include <math.h>

#define H 2048
#define IMOE 1408
#define NEXP 8
#define T_TOK 2048
#define ISH 2816
#define SCALEF 2.5f

#define NT_GU_R (IMOE / 64)   // 22
#define NT_GU_S (ISH / 64)    // 44
#define NT_DN   (H / 128)     // 16
#define GU_GRID (39 * NT_GU_R + 16 * NT_GU_S)  // 858 + 704 = 1562
#define DN_GRID (39 * NT_DN + 16 * NT_DN)      // 624 + 256 = 880

typedef __attribute__((ext_vector_type(8))) short short8;
typedef __attribute__((ext_vector_type(4))) short short4v;
typedef __attribute__((ext_vector_type(4))) float floatx4;

__device__ inline float b2f(short v) {
    unsigned int u = ((unsigned int)(unsigned short)v) << 16;
    float f; __builtin_memcpy(&f, &u, 4); return f;
}
__device__ inline short f2b(float f) {
    __hip_bfloat16 h = __float2bfloat16(f);
    short s; __builtin_memcpy(&s, &h, 2); return s;
}

// async 16B/lane global->LDS; LDS dest = wave-uniform base + lane*16
__device__ __forceinline__ void async16(const short* g, short* l) {
    __builtin_amdgcn_global_load_lds(
        (const __attribute__((address_space(1))) unsigned*)g,
        (__attribute__((address_space(3))) unsigned*)l, 16, 0, 0);
}

// Bijective XCD-aware remap (m204): hardware assigns blockIdx%8 -> XCD.
// Give each XCD a CONTIGUOUS chunk of work ids so blocks sharing a B strip
// (consecutive work ids, mt-minor) co-reside on one XCD's L2.
__device__ __forceinline__ int xcd_map(int orig, int nwg) {
    int q = nwg >> 3, r = nwg & 7;
    int x = orig & 7, s = orig >> 3;
    int base = (x < r) ? x * (q + 1) : r * (q + 1) + (x - r) * q;
    return base + s;
}

// ---------------- Router (fp32, matches reference exactly) ----------------
__global__ __launch_bounds__(256) void router_kernel(
    const float* __restrict__ x, const float* __restrict__ rw,
    const float* __restrict__ bias,
    int* __restrict__ cnt, int* __restrict__ tokList, int* __restrict__ slotList,
    float* __restrict__ pairW)
{
    const int wid  = (blockIdx.x * 256 + threadIdx.x) >> 6;
    const int lane = threadIdx.x & 63;
    if (wid >= T_TOK) return;
    const float* xr = x + (size_t)wid * H;

    float acc[NEXP];
#pragma unroll
    for (int e = 0; e < NEXP; ++e) acc[e] = 0.f;

#pragma unroll
    for (int c = 0; c < 8; ++c) {
        int idx = (c * 64 + lane) * 4;
        floatx4 xv = *(const floatx4*)(xr + idx);
#pragma unroll
        for (int e = 0; e < NEXP; ++e) {
            floatx4 wv = *(const floatx4*)(rw + e * H + idx);
            acc[e] += xv.x * wv.x + xv.y * wv.y + xv.z * wv.z + xv.w * wv.w;
        }
    }
#pragma unroll
    for (int e = 0; e < NEXP; ++e)
        for (int off = 32; off; off >>= 1)
            acc[e] += __shfl_xor(acc[e], off, 64);

    if (lane == 0) {
        float s[NEXP], sfc[NEXP];
#pragma unroll
        for (int e = 0; e < NEXP; ++e) {
            s[e]   = 1.0f / (1.0f + expf(-acc[e]));
            sfc[e] = s[e] + bias[e];
        }
        float gs[4];
#pragma unroll
        for (int g = 0; g < 4; ++g) gs[g] = sfc[2 * g] + sfc[2 * g + 1];
        int g1 = 0;
        for (int g = 1; g < 4; ++g) if (gs[g] > gs[g1]) g1 = g;
        int g2 = -1;
        for (int g = 0; g < 4; ++g) {
            if (g == g1) continue;
            if (g2 < 0 || gs[g] > gs[g2]) g2 = g;
        }
        float msk[NEXP];
#pragma unroll
        for (int e = 0; e < NEXP; ++e) {
            int g = e >> 1;
            msk[e] = (g == g1 || g == g2) ? sfc[e] : 0.0f;
        }
        int e1 = 0;
        for (int e = 1; e < NEXP; ++e) if (msk[e] > msk[e1]) e1 = e;
        int e2 = -1;
        for (int e = 0; e < NEXP; ++e) {
            if (e == e1) continue;
            if (e2 < 0 || msk[e] > msk[e2]) e2 = e;
        }
        float w1 = s[e1], w2 = s[e2];
        float inv = SCALEF / (w1 + w2 + 1e-20f);
        w1 *= inv; w2 *= inv;
        int p1 = atomicAdd(&cnt[e1], 1);
        tokList[e1 * T_TOK + p1]  = wid;
        slotList[e1 * T_TOK + p1] = 2 * wid;
        pairW[2 * wid] = w1;
        int p2 = atomicAdd(&cnt[e2], 1);
        tokList[e2 * T_TOK + p2]  = wid;
        slotList[e2 * T_TOK + p2] = 2 * wid + 1;
        pairW[2 * wid + 1] = w2;
    }
}

// ---------------- Plan ----------------
// meta[0..8]  : M per entry (entry 8 = shared, 2048)
// meta[9..17] : compact row base
// meta[20..29]: gate/up item starts
// meta[32..41]: down item starts (meta[40]=routed end)
__global__ void plan_kernel(const int* __restrict__ cnt, int* __restrict__ meta)
{
    if (blockIdx.x != 0 || threadIdx.x != 0) return;
    int base = 0, gu = 0, dn = 0;
    meta[20] = 0; meta[32] = 0;
    for (int e = 0; e < NEXP; ++e) {
        int M = cnt[e];
        meta[e] = M;
        meta[9 + e] = base;
        base += M;
        int MT = (M + 127) >> 7;
        gu += MT * NT_GU_R;
        dn += MT * NT_DN;
        meta[21 + e] = gu;
        meta[33 + e] = dn;
    }
    meta[8]  = T_TOK;   // shared M
    meta[17] = 0;       // shared base (separate buffer)
    meta[29] = gu + 16 * NT_GU_S;
    meta[41] = dn + 16 * NT_DN;
}

// ---------------- fp32 -> bf16 convert (x only) ----------------
__global__ __launch_bounds__(256) void convert_kernel(
    const float* __restrict__ src, short* __restrict__ dst, int n4)
{
    int idx = blockIdx.x * 256 + threadIdx.x;
    int stride = gridDim.x * 256;
    for (; idx < n4; idx += stride) {
        floatx4 v = *(const floatx4*)(src + (size_t)idx * 4);
        short4v o = { f2b(v.x), f2b(v.y), f2b(v.z), f2b(v.w) };
        *(short4v*)(dst + (size_t)idx * 4) = o;
    }
}

// ---------------- fp32 -> bf16 weight pre-convert (all 6 weight tensors) ----
// Removes the fp32->bf16 cvt from BOTH GEMM inner loops (round-2 theory:
// GEMMs were VALU/latency-bound on in-loop B convert, not HBM-bound).
// Pure streaming: 346 MB read + 173 MB write.
// Unit = 8 floats (2x floatx4 load, 1x short8 store).
#define W8_GU  2883584   // 8*1408*2048/8  (gw, uw, dw each)
#define W8_SH  720896    // 2816*2048/8    (sgw, suw, sdw each)
#define W8_S1  (W8_GU)
#define W8_S2  (2*W8_GU)
#define W8_S3  (3*W8_GU)
#define W8_S4  (3*W8_GU + W8_SH)
#define W8_S5  (3*W8_GU + 2*W8_SH)
#define W8_S6  (3*W8_GU + 3*W8_SH)
__global__ __launch_bounds__(256) void wconvert_kernel(
    const float* __restrict__ gw, const float* __restrict__ uw,
    const float* __restrict__ dw, const float* __restrict__ sgw,
    const float* __restrict__ suw, const float* __restrict__ sdw,
    short* __restrict__ gwb, short* __restrict__ uwb, short* __restrict__ dwb,
    short* __restrict__ sgwb, short* __restrict__ suwb, short* __restrict__ sdwb)
{
    int idx = blockIdx.x * 256 + threadIdx.x;
    int stride = gridDim.x * 256;
    for (; idx < W8_S6; idx += stride) {
        const float* s; short* d; int local;
        if (idx < W8_S3) {
            if (idx < W8_S1)      { s = gw;  d = gwb;  local = idx; }
            else if (idx < W8_S2) { s = uw;  d = uwb;  local = idx - W8_S1; }
            else                  { s = dw;  d = dwb;  local = idx - W8_S2; }
        } else {
            if (idx < W8_S4)      { s = sgw; d = sgwb; local = idx - W8_S3; }
            else if (idx < W8_S5) { s = suw; d = suwb; local = idx - W8_S4; }
            else                  { s = sdw; d = sdwb; local = idx - W8_S5; }
        }
        floatx4 v0 = *(const floatx4*)(s + (size_t)local * 8);
        floatx4 v1 = *(const floatx4*)(s + (size_t)local * 8 + 4);
        short8 o = { f2b(v0.x), f2b(v0.y), f2b(v0.z), f2b(v0.w),
                     f2b(v1.x), f2b(v1.y), f2b(v1.z), f2b(v1.w) };
        *(short8*)(d + (size_t)local * 8) = o;
    }
}

// ---------------- Fused gate+up grouped GEMM ----------------
// BM=128, BN=64 per matrix (g,u staged in one 128-row LDS buffer), BK=64,
// K=2048. A and B both bf16, both staged via async16 (global_load_lds) with
// pre-swizzled source / linear LDS dest / XOR-swizzled read. No in-loop VALU
// convert. Epilogue: silu(g)*u -> compact hidden (bf16).
__global__ __launch_bounds__(256) void gu_gemm(
    const short* __restrict__ xb,
    const short* __restrict__ gwb, const short* __restrict__ uwb,
    const short* __restrict__ sgwb, const short* __restrict__ suwb,
    short* __restrict__ hiddenP, short* __restrict__ hiddenS,
    const int* __restrict__ tokList, const int* __restrict__ meta)
{
    const int total = meta[29];
    if (blockIdx.x >= total) return;
    const int idx = xcd_map(blockIdx.x, total);
    int e = 0;
    while (e < 8 && idx >= meta[21 + e]) ++e;

    int M, NT, Nout, rowBase;
    const short *b1, *b2;
    const int* gat;
    short* outP;
    if (e < 8) {
        M = meta[e]; NT = NT_GU_R; Nout = IMOE; rowBase = meta[9 + e];
        b1 = gwb + (size_t)e * IMOE * H;
        b2 = uwb + (size_t)e * IMOE * H;
        gat = tokList + e * T_TOK;
        outP = hiddenP;
    } else {
        M = T_TOK; NT = NT_GU_S; Nout = ISH; rowBase = 0;
        b1 = sgwb; b2 = suwb; gat = nullptr; outP = hiddenS;
    }
    const int MT = (M + 127) >> 7;
    const int local = idx - meta[20 + e];
    const int mt = local % MT;          // mt-minor: adjacent blocks share weight tile
    const int nt = local / MT;

    __shared__ short As[128 * 64];
    __shared__ short Bgu[128 * 64];     // rows 0..63 = gate, 64..127 = up

    const int tid  = threadIdx.x;
    const int w    = tid >> 6;
    const int lane = tid & 63;
    const int quad = lane >> 4;
    const int l16  = lane & 15;
    const int wm = w >> 1, wn = w & 1;

    // staging geometry: wave w covers rows w*32+i*8+r8 (i=0..3), 8 rows/iter,
    // lane -> (row r8=lane>>3, phys chunk lane&7); source chunk = (lane&7)^r8
    const int r8 = lane >> 3;
    const int cs = (lane & 7) ^ r8;
    const short* aSrc[4];
    const short* bSrc[4];
    short* ldsA[4];
    short* ldsB[4];
#pragma unroll
    for (int i = 0; i < 4; ++i) {
        int r = w * 32 + i * 8 + r8;
        int p = mt * 128 + r;
        int pos = p < M ? p : (M - 1);
        int arow = gat ? gat[pos] : pos;
        aSrc[i] = xb + (size_t)arow * H + cs * 8;
        ldsA[i] = As + (w * 32 + i * 8) * 64;
        // B: combined row r -> gate row r (r<64) or up row r-64
        const short* wsrc = (r < 64) ? (b1 + (size_t)(nt * 64 + r) * H)
                                     : (b2 + (size_t)(nt * 64 + r - 64) * H);
        bSrc[i] = wsrc + cs * 8;
        ldsB[i] = Bgu + (w * 32 + i * 8) * 64;
    }

    floatx4 accg[4][2] = {};
    floatx4 accu[4][2] = {};

    for (int k0 = 0; k0 < H; k0 += 64) {
#pragma unroll
        for (int i = 0; i < 4; ++i) async16(aSrc[i] + k0, ldsA[i]);
#pragma unroll
        for (int i = 0; i < 4; ++i) async16(bSrc[i] + k0, ldsB[i]);
        __syncthreads();
        const int sw = l16 & 7;
        short8 af[4], bgf[2], buf[2];
#pragma unroll
        for (int kk2 = 0; kk2 < 2; ++kk2) {
            const int c = kk2 * 4 + quad;
#pragma unroll
            for (int m = 0; m < 4; ++m)
                af[m] = *(const short8*)(As + (wm * 64 + m * 16 + l16) * 64 + (c ^ sw) * 8);
#pragma unroll
            for (int n = 0; n < 2; ++n) {
                bgf[n] = *(const short8*)(Bgu + (wn * 32 + n * 16 + l16) * 64 + (c ^ sw) * 8);
                buf[n] = *(const short8*)(Bgu + (64 + wn * 32 + n * 16 + l16) * 64 + (c ^ sw) * 8);
            }
#pragma unroll
            for (int m = 0; m < 4; ++m)
#pragma unroll
                for (int n = 0; n < 2; ++n) {
                    accg[m][n] = __builtin_amdgcn_mfma_f32_16x16x32_bf16(af[m], bgf[n], accg[m][n], 0, 0, 0);
                    accu[m][n] = __builtin_amdgcn_mfma_f32_16x16x32_bf16(af[m], buf[n], accu[m][n], 0, 0, 0);
                }
        }
        __syncthreads();
    }

    // epilogue: silu(g)*u -> compact hidden. C/D layout: col=l16, row=quad*4+rr
#pragma unroll
    for (int m = 0; m < 4; ++m) {
#pragma unroll
        for (int rr = 0; rr < 4; ++rr) {
            int lr = wm * 64 + m * 16 + quad * 4 + rr;
            int p = mt * 128 + lr;
            if (p >= M) continue;
            size_t rowoff = (size_t)(rowBase + p) * Nout + nt * 64 + wn * 32;
#pragma unroll
            for (int n = 0; n < 2; ++n) {
                float g = accg[m][n][rr];
                float u = accu[m][n][rr];
                outP[rowoff + n * 16 + l16] = f2b(g / (1.0f + __expf(-g)) * u);
            }
        }
    }
}

// ---------------- Down grouped GEMM ----------------
// BM=128, BN=128, BK=64, K = 1408 (routed) / 2816 (shared). bf16 B via
// async16. Per-range XCD remap (routed and shared independently) keeps both
// L2 locality and per-XCD work balance (round-1 lesson: single-range remap
// piled all K=2816 tiles on 2 XCDs -> 1.5x makespan).
__global__ __launch_bounds__(256) void dn_gemm(
    const short* __restrict__ hiddenP, const short* __restrict__ hiddenS,
    const short* __restrict__ dwb, const short* __restrict__ sdwb,
    short* __restrict__ outPairs, short* __restrict__ sharedOut,
    const int* __restrict__ slotList, const int* __restrict__ meta)
{
    const int total = meta[41];
    if (blockIdx.x >= total) return;
    const int rtot = meta[40];
    int idx;
    if (blockIdx.x < rtot) idx = xcd_map(blockIdx.x, rtot);
    else                   idx = rtot + xcd_map(blockIdx.x - rtot, total - rtot);
    int e = 0;
    while (e < 8 && idx >= meta[33 + e]) ++e;

    int M, K, rowBase;
    const short* bp;
    const short* Abase;
    const int* scat;
    short* outP;
    if (e < 8) {
        M = meta[e]; K = IMOE; rowBase = meta[9 + e];
        bp = dwb + (size_t)e * H * IMOE;
        Abase = hiddenP; scat = slotList + e * T_TOK; outP = outPairs;
    } else {
        M = T_TOK; K = ISH; rowBase = 0;
        bp = sdwb; Abase = hiddenS; scat = nullptr; outP = sharedOut;
    }
    const int MT = (M + 127) >> 7;
    const int local = idx - meta[32 + e];
    const int mt = local % MT;
    const int nt = local / MT;

    __shared__ short As[128 * 64];
    __shared__ short Bs[128 * 64];

    const int tid  = threadIdx.x;
    const int w    = tid >> 6;
    const int lane = tid & 63;
    const int quad = lane >> 4;
    const int l16  = lane & 15;
    const int wm = w >> 1, wn = w & 1;

    const int r8 = lane >> 3;
    const int cs = (lane & 7) ^ r8;
    const short* aSrc[4];
    const short* bSrc[4];
    short* ldsA[4];
    short* ldsB[4];
#pragma unroll
    for (int i = 0; i < 4; ++i) {
        int r = w * 32 + i * 8 + r8;
        int p = mt * 128 + r;
        int pos = p < M ? p : (M - 1);
        aSrc[i] = Abase + (size_t)(rowBase + pos) * K + cs * 8;
        ldsA[i] = As + (w * 32 + i * 8) * 64;
        bSrc[i] = bp + (size_t)(nt * 128 + r) * K + cs * 8;
        ldsB[i] = Bs + (w * 32 + i * 8) * 64;
    }

    floatx4 acc[4][4] = {};

    const int kIters = K >> 6;
    for (int kt = 0; kt < kIters; ++kt) {
        const int k0 = kt << 6;
#pragma unroll
        for (int i = 0; i < 4; ++i) async16(aSrc[i] + k0, ldsA[i]);
#pragma unroll
        for (int i = 0; i < 4; ++i) async16(bSrc[i] + k0, ldsB[i]);
        __syncthreads();
        const int sw = l16 & 7;
        short8 af[4], bf[4];
#pragma unroll
        for (int kk2 = 0; kk2 < 2; ++kk2) {
            const int c = kk2 * 4 + quad;
#pragma unroll
            for (int m = 0; m < 4; ++m)
                af[m] = *(const short8*)(As + (wm * 64 + m * 16 + l16) * 64 + (c ^ sw) * 8);
#pragma unroll
            for (int n = 0; n < 4; ++n)
                bf[n] = *(const short8*)(Bs + (wn * 64 + n * 16 + l16) * 64 + (c ^ sw) * 8);
#pragma unroll
            for (int m = 0; m < 4; ++m)
#pragma unroll
                for (int n = 0; n < 4; ++n)
                    acc[m][n] = __builtin_amdgcn_mfma_f32_16x16x32_bf16(af[m], bf[n], acc[m][n], 0, 0, 0);
        }
        __syncthreads();
    }

#pragma unroll
    for (int m = 0; m < 4; ++m) {
#pragma unroll
        for (int rr = 0; rr < 4; ++rr) {
            int lr = wm * 64 + m * 16 + quad * 4 + rr;
            int p = mt * 128 + lr;
            if (p >= M) continue;
            int crow = scat ? scat[p] : p;
            size_t rowoff = (size_t)crow * H + nt * 128 + wn * 64;
#pragma unroll
            for (int n = 0; n < 4; ++n)
                outP[rowoff + n * 16 + l16] = f2b(acc[m][n][rr]);
        }
    }
}

// ---------------- Combine ----------------
__global__ __launch_bounds__(256) void combine_kernel(
    const short* __restrict__ outPairs, const short* __restrict__ sharedOut,
    const float* __restrict__ pairW, float* __restrict__ out)
{
    size_t gi = ((size_t)blockIdx.x * 256 + threadIdx.x) * 8;
    int t = (int)(gi >> 11);
    int h = (int)(gi & (H - 1));
    float w0 = pairW[2 * t], w1 = pairW[2 * t + 1];
    short8 p0 = *(const short8*)(outPairs + (size_t)(2 * t) * H + h);
    short8 p1 = *(const short8*)(outPairs + (size_t)(2 * t + 1) * H + h);
    short8 sh = *(const short8*)(sharedOut + gi);
    floatx4 o0, o1;
#pragma unroll
    for (int j = 0; j < 4; ++j)
        o0[j] = w0 * b2f(p0[j]) + w1 * b2f(p1[j]) + b2f(sh[j]);
#pragma unroll
    for (int j = 0; j < 4; ++j)
        o1[j] = w0 * b2f(p0[4 + j]) + w1 * b2f(p1[4 + j]) + b2f(sh[4 + j]);
    *(floatx4*)(out + gi)     = o0;
    *(floatx4*)(out + gi + 4) = o1;
}

extern "C" void kernel_launch(void* const* d_in, const int* in_sizes, int n_in,
                              void* d_out, int out_size, void* d_ws, size_t ws_size,
                              hipStream_t stream)
{
    const float* x    = (const float*)d_in[0];
    const float* rw   = (const float*)d_in[1];
    const float* bias = (const float*)d_in[2];
    const float* gw   = (const float*)d_in[3];
    const float* uw   = (const float*)d_in[4];
    const float* dw   = (const float*)d_in[5];
    const float* sgw  = (const float*)d_in[6];
    const float* suw  = (const float*)d_in[7];
    const float* sdw  = (const float*)d_in[8];
    float* out = (float*)d_out;

    char* ws = (char*)d_ws;
    size_t off = 0;
    auto alloc = [&](size_t bytes) {
        off = (off + 255) & ~(size_t)255;
        void* p = ws + off;
        off += bytes;
        return p;
    };
    int*   cnt       = (int*)  alloc(NEXP * sizeof(int));
    int*   tokList   = (int*)  alloc((size_t)NEXP * T_TOK * sizeof(int));
    int*   slotList  = (int*)  alloc((size_t)NEXP * T_TOK * sizeof(int));
    float* pairW     = (float*)alloc((size_t)2 * T_TOK * sizeof(float));
    int*   meta      = (int*)  alloc(64 * sizeof(int));
    short* xb        = (short*)alloc((size_t)T_TOK * H * sizeof(short));
    short* hiddenP   = (short*)alloc((size_t)2 * T_TOK * IMOE * sizeof(short));
    short* hiddenS   = (short*)alloc((size_t)T_TOK * ISH * sizeof(short));
    short* outPairs  = (short*)alloc((size_t)2 * T_TOK * H * sizeof(short));
    short* sharedOut = (short*)alloc((size_t)T_TOK * H * sizeof(short));
    // bf16 weight copies (~173 MB total)
    short* gwb  = (short*)alloc((size_t)NEXP * IMOE * H * sizeof(short));
    short* uwb  = (short*)alloc((size_t)NEXP * IMOE * H * sizeof(short));
    short* dwb  = (short*)alloc((size_t)NEXP * H * IMOE * sizeof(short));
    short* sgwb = (short*)alloc((size_t)ISH * H * sizeof(short));
    short* suwb = (short*)alloc((size_t)ISH * H * sizeof(short));
    short* sdwb = (short*)alloc((size_t)H * ISH * sizeof(short));
    (void)ws_size;

    hipMemsetAsync(cnt, 0, NEXP * sizeof(int), stream);

    router_kernel<<<T_TOK / 4, 256, 0, stream>>>(x, rw, bias, cnt, tokList, slotList, pairW);
    plan_kernel<<<1, 64, 0, stream>>>(cnt, meta);
    convert_kernel<<<2048, 256, 0, stream>>>(x, xb, T_TOK * H / 4);
    wconvert_kernel<<<2048, 256, 0, stream>>>(gw, uw, dw, sgw, suw, sdw,
                                              gwb, uwb, dwb, sgwb, suwb, sdwb);

    gu_gemm<<<GU_GRID, 256, 0, stream>>>(xb, gwb, uwb, sgwb, suwb,
                                         hiddenP, hiddenS, tokList, meta);
    dn_gemm<<<DN_GRID, 256, 0, stream>>>(hiddenP, hiddenS, dwb, sdwb,
                                         outPairs, sharedOut, slotList, meta);

    combine_kernel<<<(T_TOK * H / 8) / 256, 256, 0, stream>>>(outPairs, sharedOut, pairW, out);
}

// Round 4
// 652.961 us; speedup vs baseline: 1.1334x; 1.0071x over previous
//
#include <hip/hip_runtime.h>
#include <hip/hip_bf16.h>
#include <math.h>

#define H 2048
#define IMOE 1408
#define NEXP 8
#define T_TOK 2048
#define ISH 2816
#define SCALEF 2.5f

#define NT_GU_R (IMOE / 64)   // 22
#define NT_GU_S (ISH / 64)    // 44
#define NT_DN   (H / 128)     // 16
#define GU_GRID (39 * NT_GU_R + 16 * NT_GU_S)  // 858 + 704 = 1562
#define DN_GRID (39 * NT_DN + 16 * NT_DN)      // 624 + 256 = 880
#define LDS_HALF (128 * 64)   // shorts per buffer half

typedef __attribute__((ext_vector_type(8))) short short8;
typedef __attribute__((ext_vector_type(4))) short short4v;
typedef __attribute__((ext_vector_type(4))) float floatx4;

__device__ inline float b2f(short v) {
    unsigned int u = ((unsigned int)(unsigned short)v) << 16;
    float f; __builtin_memcpy(&f, &u, 4); return f;
}
__device__ inline short f2b(float f) {
    __hip_bfloat16 h = __float2bfloat16(f);
    short s; __builtin_memcpy(&s, &h, 2); return s;
}

// async 16B/lane global->LDS; LDS dest = wave-uniform base + lane*16
__device__ __forceinline__ void async16(const short* g, short* l) {
    __builtin_amdgcn_global_load_lds(
        (const __attribute__((address_space(1))) unsigned*)g,
        (__attribute__((address_space(3))) unsigned*)l, 16, 0, 0);
}

// Bijective XCD-aware remap (m204): hardware assigns blockIdx%8 -> XCD.
__device__ __forceinline__ int xcd_map(int orig, int nwg) {
    int q = nwg >> 3, r = nwg & 7;
    int x = orig & 7, s = orig >> 3;
    int base = (x < r) ? x * (q + 1) : r * (q + 1) + (x - r) * q;
    return base + s;
}

// ---------------- Router (fp32, matches reference exactly) ----------------
__global__ __launch_bounds__(256) void router_kernel(
    const float* __restrict__ x, const float* __restrict__ rw,
    const float* __restrict__ bias,
    int* __restrict__ cnt, int* __restrict__ tokList, int* __restrict__ slotList,
    float* __restrict__ pairW)
{
    const int wid  = (blockIdx.x * 256 + threadIdx.x) >> 6;
    const int lane = threadIdx.x & 63;
    if (wid >= T_TOK) return;
    const float* xr = x + (size_t)wid * H;

    float acc[NEXP];
#pragma unroll
    for (int e = 0; e < NEXP; ++e) acc[e] = 0.f;

#pragma unroll
    for (int c = 0; c < 8; ++c) {
        int idx = (c * 64 + lane) * 4;
        floatx4 xv = *(const floatx4*)(xr + idx);
#pragma unroll
        for (int e = 0; e < NEXP; ++e) {
            floatx4 wv = *(const floatx4*)(rw + e * H + idx);
            acc[e] += xv.x * wv.x + xv.y * wv.y + xv.z * wv.z + xv.w * wv.w;
        }
    }
#pragma unroll
    for (int e = 0; e < NEXP; ++e)
        for (int off = 32; off; off >>= 1)
            acc[e] += __shfl_xor(acc[e], off, 64);

    if (lane == 0) {
        float s[NEXP], sfc[NEXP];
#pragma unroll
        for (int e = 0; e < NEXP; ++e) {
            s[e]   = 1.0f / (1.0f + expf(-acc[e]));
            sfc[e] = s[e] + bias[e];
        }
        float gs[4];
#pragma unroll
        for (int g = 0; g < 4; ++g) gs[g] = sfc[2 * g] + sfc[2 * g + 1];
        int g1 = 0;
        for (int g = 1; g < 4; ++g) if (gs[g] > gs[g1]) g1 = g;
        int g2 = -1;
        for (int g = 0; g < 4; ++g) {
            if (g == g1) continue;
            if (g2 < 0 || gs[g] > gs[g2]) g2 = g;
        }
        float msk[NEXP];
#pragma unroll
        for (int e = 0; e < NEXP; ++e) {
            int g = e >> 1;
            msk[e] = (g == g1 || g == g2) ? sfc[e] : 0.0f;
        }
        int e1 = 0;
        for (int e = 1; e < NEXP; ++e) if (msk[e] > msk[e1]) e1 = e;
        int e2 = -1;
        for (int e = 0; e < NEXP; ++e) {
            if (e == e1) continue;
            if (e2 < 0 || msk[e] > msk[e2]) e2 = e;
        }
        float w1 = s[e1], w2 = s[e2];
        float inv = SCALEF / (w1 + w2 + 1e-20f);
        w1 *= inv; w2 *= inv;
        int p1 = atomicAdd(&cnt[e1], 1);
        tokList[e1 * T_TOK + p1]  = wid;
        slotList[e1 * T_TOK + p1] = 2 * wid;
        pairW[2 * wid] = w1;
        int p2 = atomicAdd(&cnt[e2], 1);
        tokList[e2 * T_TOK + p2]  = wid;
        slotList[e2 * T_TOK + p2] = 2 * wid + 1;
        pairW[2 * wid + 1] = w2;
    }
}

// ---------------- Plan ----------------
// meta[0..8]  : M per entry (entry 8 = shared, 2048)
// meta[9..17] : compact row base
// meta[20..29]: gate/up item starts
// meta[32..41]: down item starts (meta[40]=routed end)
__global__ void plan_kernel(const int* __restrict__ cnt, int* __restrict__ meta)
{
    if (blockIdx.x != 0 || threadIdx.x != 0) return;
    int base = 0, gu = 0, dn = 0;
    meta[20] = 0; meta[32] = 0;
    for (int e = 0; e < NEXP; ++e) {
        int M = cnt[e];
        meta[e] = M;
        meta[9 + e] = base;
        base += M;
        int MT = (M + 127) >> 7;
        gu += MT * NT_GU_R;
        dn += MT * NT_DN;
        meta[21 + e] = gu;
        meta[33 + e] = dn;
    }
    meta[8]  = T_TOK;   // shared M
    meta[17] = 0;       // shared base (separate buffer)
    meta[29] = gu + 16 * NT_GU_S;
    meta[41] = dn + 16 * NT_DN;
}

// ---------------- fp32 -> bf16 convert (x only) ----------------
__global__ __launch_bounds__(256) void convert_kernel(
    const float* __restrict__ src, short* __restrict__ dst, int n4)
{
    int idx = blockIdx.x * 256 + threadIdx.x;
    int stride = gridDim.x * 256;
    for (; idx < n4; idx += stride) {
        floatx4 v = *(const floatx4*)(src + (size_t)idx * 4);
        short4v o = { f2b(v.x), f2b(v.y), f2b(v.z), f2b(v.w) };
        *(short4v*)(dst + (size_t)idx * 4) = o;
    }
}

// ---------------- fp32 -> bf16 weight pre-convert (all 6 weight tensors) ----
#define W8_GU  2883584   // 8*1408*2048/8  (gw, uw, dw each)
#define W8_SH  720896    // 2816*2048/8    (sgw, suw, sdw each)
#define W8_S1  (W8_GU)
#define W8_S2  (2*W8_GU)
#define W8_S3  (3*W8_GU)
#define W8_S4  (3*W8_GU + W8_SH)
#define W8_S5  (3*W8_GU + 2*W8_SH)
#define W8_S6  (3*W8_GU + 3*W8_SH)
__global__ __launch_bounds__(256) void wconvert_kernel(
    const float* __restrict__ gw, const float* __restrict__ uw,
    const float* __restrict__ dw, const float* __restrict__ sgw,
    const float* __restrict__ suw, const float* __restrict__ sdw,
    short* __restrict__ gwb, short* __restrict__ uwb, short* __restrict__ dwb,
    short* __restrict__ sgwb, short* __restrict__ suwb, short* __restrict__ sdwb)
{
    int idx = blockIdx.x * 256 + threadIdx.x;
    int stride = gridDim.x * 256;
    for (; idx < W8_S6; idx += stride) {
        const float* s; short* d; int local;
        if (idx < W8_S3) {
            if (idx < W8_S1)      { s = gw;  d = gwb;  local = idx; }
            else if (idx < W8_S2) { s = uw;  d = uwb;  local = idx - W8_S1; }
            else                  { s = dw;  d = dwb;  local = idx - W8_S2; }
        } else {
            if (idx < W8_S4)      { s = sgw; d = sgwb; local = idx - W8_S3; }
            else if (idx < W8_S5) { s = suw; d = suwb; local = idx - W8_S4; }
            else                  { s = sdw; d = sdwb; local = idx - W8_S5; }
        }
        floatx4 v0 = *(const floatx4*)(s + (size_t)local * 8);
        floatx4 v1 = *(const floatx4*)(s + (size_t)local * 8 + 4);
        short8 o = { f2b(v0.x), f2b(v0.y), f2b(v0.z), f2b(v0.w),
                     f2b(v1.x), f2b(v1.y), f2b(v1.z), f2b(v1.w) };
        *(short8*)(d + (size_t)local * 8) = o;
    }
}

// ---------------- Fused gate+up grouped GEMM ----------------
// BM=128, BN=64 per matrix, BK=64, K=2048. Double-buffered LDS (T3 minimum
// 2-phase): stage next K-tile BEFORE computing current; raw s_barrier +
// counted s_waitcnt vmcnt(8) so next-tile loads stay in flight across the
// barrier (round-3 theory: vmcnt(0)-drain at __syncthreads was the stall at
// ~1.7 blocks/CU implicit overlap).
// Hazards: STAGE into buf 1-cur issues only after the end-of-compute barrier
// of the iteration that last read buf 1-cur; per-wave vmcnt(8) before the
// pre-compute barrier => all waves' current-tile loads landed.
__global__ __launch_bounds__(256) void gu_gemm(
    const short* __restrict__ xb,
    const short* __restrict__ gwb, const short* __restrict__ uwb,
    const short* __restrict__ sgwb, const short* __restrict__ suwb,
    short* __restrict__ hiddenP, short* __restrict__ hiddenS,
    const int* __restrict__ tokList, const int* __restrict__ meta)
{
    const int total = meta[29];
    if (blockIdx.x >= total) return;
    const int idx = xcd_map(blockIdx.x, total);
    int e = 0;
    while (e < 8 && idx >= meta[21 + e]) ++e;

    int M, NT, Nout, rowBase;
    const short *b1, *b2;
    const int* gat;
    short* outP;
    if (e < 8) {
        M = meta[e]; NT = NT_GU_R; Nout = IMOE; rowBase = meta[9 + e];
        b1 = gwb + (size_t)e * IMOE * H;
        b2 = uwb + (size_t)e * IMOE * H;
        gat = tokList + e * T_TOK;
        outP = hiddenP;
    } else {
        M = T_TOK; NT = NT_GU_S; Nout = ISH; rowBase = 0;
        b1 = sgwb; b2 = suwb; gat = nullptr; outP = hiddenS;
    }
    const int MT = (M + 127) >> 7;
    const int local = idx - meta[20 + e];
    const int mt = local % MT;          // mt-minor: adjacent blocks share weight tile
    const int nt = local / MT;

    __shared__ short As[2 * LDS_HALF];
    __shared__ short Bgu[2 * LDS_HALF];   // rows 0..63 = gate, 64..127 = up

    const int tid  = threadIdx.x;
    const int w    = tid >> 6;
    const int lane = tid & 63;
    const int quad = lane >> 4;
    const int l16  = lane & 15;
    const int wm = w >> 1, wn = w & 1;

    const int r8 = lane >> 3;
    const int cs = (lane & 7) ^ r8;
    const short* aSrc[4];
    const short* bSrc[4];
    short* ldsA[4];
    short* ldsB[4];
#pragma unroll
    for (int i = 0; i < 4; ++i) {
        int r = w * 32 + i * 8 + r8;
        int p = mt * 128 + r;
        int pos = p < M ? p : (M - 1);
        int arow = gat ? gat[pos] : pos;
        aSrc[i] = xb + (size_t)arow * H + cs * 8;
        ldsA[i] = As + (w * 32 + i * 8) * 64;
        const short* wsrc = (r < 64) ? (b1 + (size_t)(nt * 64 + r) * H)
                                     : (b2 + (size_t)(nt * 64 + r - 64) * H);
        bSrc[i] = wsrc + cs * 8;
        ldsB[i] = Bgu + (w * 32 + i * 8) * 64;
    }

    floatx4 accg[4][2] = {};
    floatx4 accu[4][2] = {};

    // prologue: stage tile 0 into buffer 0
#pragma unroll
    for (int i = 0; i < 4; ++i) { async16(aSrc[i], ldsA[i]); async16(bSrc[i], ldsB[i]); }

    int cur = 0;
    for (int k0 = 0; k0 < H; k0 += 64) {
        const int nk = k0 + 64;
        if (nk < H) {
            const int noff = (cur ^ 1) * LDS_HALF;
#pragma unroll
            for (int i = 0; i < 4; ++i) {
                async16(aSrc[i] + nk, ldsA[i] + noff);
                async16(bSrc[i] + nk, ldsB[i] + noff);
            }
            asm volatile("s_waitcnt vmcnt(8)" ::: "memory");
        } else {
            asm volatile("s_waitcnt vmcnt(0)" ::: "memory");
        }
        __builtin_amdgcn_s_barrier();

        const short* Ab = As  + cur * LDS_HALF;
        const short* Bb = Bgu + cur * LDS_HALF;
        const int sw = l16 & 7;
        short8 af[4], bgf[2], buf[2];
#pragma unroll
        for (int kk2 = 0; kk2 < 2; ++kk2) {
            const int c = kk2 * 4 + quad;
#pragma unroll
            for (int m = 0; m < 4; ++m)
                af[m] = *(const short8*)(Ab + (wm * 64 + m * 16 + l16) * 64 + (c ^ sw) * 8);
#pragma unroll
            for (int n = 0; n < 2; ++n) {
                bgf[n] = *(const short8*)(Bb + (wn * 32 + n * 16 + l16) * 64 + (c ^ sw) * 8);
                buf[n] = *(const short8*)(Bb + (64 + wn * 32 + n * 16 + l16) * 64 + (c ^ sw) * 8);
            }
#pragma unroll
            for (int m = 0; m < 4; ++m)
#pragma unroll
                for (int n = 0; n < 2; ++n) {
                    accg[m][n] = __builtin_amdgcn_mfma_f32_16x16x32_bf16(af[m], bgf[n], accg[m][n], 0, 0, 0);
                    accu[m][n] = __builtin_amdgcn_mfma_f32_16x16x32_bf16(af[m], buf[n], accu[m][n], 0, 0, 0);
                }
        }
        __builtin_amdgcn_s_barrier();
        cur ^= 1;
    }

    // epilogue: silu(g)*u -> compact hidden. C/D layout: col=l16, row=quad*4+rr
#pragma unroll
    for (int m = 0; m < 4; ++m) {
#pragma unroll
        for (int rr = 0; rr < 4; ++rr) {
            int lr = wm * 64 + m * 16 + quad * 4 + rr;
            int p = mt * 128 + lr;
            if (p >= M) continue;
            size_t rowoff = (size_t)(rowBase + p) * Nout + nt * 64 + wn * 32;
#pragma unroll
            for (int n = 0; n < 2; ++n) {
                float g = accg[m][n][rr];
                float u = accu[m][n][rr];
                outP[rowoff + n * 16 + l16] = f2b(g / (1.0f + __expf(-g)) * u);
            }
        }
    }
}

// ---------------- Down grouped GEMM ----------------
// BM=128, BN=128, BK=64, K = 1408 (routed) / 2816 (shared). Same 2-phase
// double-buffered pipeline. Per-range XCD remap (routed and shared
// independently) keeps L2 locality AND per-XCD work balance.
__global__ __launch_bounds__(256) void dn_gemm(
    const short* __restrict__ hiddenP, const short* __restrict__ hiddenS,
    const short* __restrict__ dwb, const short* __restrict__ sdwb,
    short* __restrict__ outPairs, short* __restrict__ sharedOut,
    const int* __restrict__ slotList, const int* __restrict__ meta)
{
    const int total = meta[41];
    if (blockIdx.x >= total) return;
    const int rtot = meta[40];
    int idx;
    if (blockIdx.x < rtot) idx = xcd_map(blockIdx.x, rtot);
    else                   idx = rtot + xcd_map(blockIdx.x - rtot, total - rtot);
    int e = 0;
    while (e < 8 && idx >= meta[33 + e]) ++e;

    int M, K, rowBase;
    const short* bp;
    const short* Abase;
    const int* scat;
    short* outP;
    if (e < 8) {
        M = meta[e]; K = IMOE; rowBase = meta[9 + e];
        bp = dwb + (size_t)e * H * IMOE;
        Abase = hiddenP; scat = slotList + e * T_TOK; outP = outPairs;
    } else {
        M = T_TOK; K = ISH; rowBase = 0;
        bp = sdwb; Abase = hiddenS; scat = nullptr; outP = sharedOut;
    }
    const int MT = (M + 127) >> 7;
    const int local = idx - meta[32 + e];
    const int mt = local % MT;
    const int nt = local / MT;

    __shared__ short As[2 * LDS_HALF];
    __shared__ short Bs[2 * LDS_HALF];

    const int tid  = threadIdx.x;
    const int w    = tid >> 6;
    const int lane = tid & 63;
    const int quad = lane >> 4;
    const int l16  = lane & 15;
    const int wm = w >> 1, wn = w & 1;

    const int r8 = lane >> 3;
    const int cs = (lane & 7) ^ r8;
    const short* aSrc[4];
    const short* bSrc[4];
    short* ldsA[4];
    short* ldsB[4];
#pragma unroll
    for (int i = 0; i < 4; ++i) {
        int r = w * 32 + i * 8 + r8;
        int p = mt * 128 + r;
        int pos = p < M ? p : (M - 1);
        aSrc[i] = Abase + (size_t)(rowBase + pos) * K + cs * 8;
        ldsA[i] = As + (w * 32 + i * 8) * 64;
        bSrc[i] = bp + (size_t)(nt * 128 + r) * K + cs * 8;
        ldsB[i] = Bs + (w * 32 + i * 8) * 64;
    }

    floatx4 acc[4][4] = {};

    // prologue
#pragma unroll
    for (int i = 0; i < 4; ++i) { async16(aSrc[i], ldsA[i]); async16(bSrc[i], ldsB[i]); }

    const int kIters = K >> 6;
    int cur = 0;
    for (int kt = 0; kt < kIters; ++kt) {
        const int nk = (kt + 1) << 6;
        if (kt + 1 < kIters) {
            const int noff = (cur ^ 1) * LDS_HALF;
#pragma unroll
            for (int i = 0; i < 4; ++i) {
                async16(aSrc[i] + nk, ldsA[i] + noff);
                async16(bSrc[i] + nk, ldsB[i] + noff);
            }
            asm volatile("s_waitcnt vmcnt(8)" ::: "memory");
        } else {
            asm volatile("s_waitcnt vmcnt(0)" ::: "memory");
        }
        __builtin_amdgcn_s_barrier();

        const short* Ab = As + cur * LDS_HALF;
        const short* Bb = Bs + cur * LDS_HALF;
        const int sw = l16 & 7;
        short8 af[4], bf[4];
#pragma unroll
        for (int kk2 = 0; kk2 < 2; ++kk2) {
            const int c = kk2 * 4 + quad;
#pragma unroll
            for (int m = 0; m < 4; ++m)
                af[m] = *(const short8*)(Ab + (wm * 64 + m * 16 + l16) * 64 + (c ^ sw) * 8);
#pragma unroll
            for (int n = 0; n < 4; ++n)
                bf[n] = *(const short8*)(Bb + (wn * 64 + n * 16 + l16) * 64 + (c ^ sw) * 8);
#pragma unroll
            for (int m = 0; m < 4; ++m)
#pragma unroll
                for (int n = 0; n < 4; ++n)
                    acc[m][n] = __builtin_amdgcn_mfma_f32_16x16x32_bf16(af[m], bf[n], acc[m][n], 0, 0, 0);
        }
        __builtin_amdgcn_s_barrier();
        cur ^= 1;
    }

#pragma unroll
    for (int m = 0; m < 4; ++m) {
#pragma unroll
        for (int rr = 0; rr < 4; ++rr) {
            int lr = wm * 64 + m * 16 + quad * 4 + rr;
            int p = mt * 128 + lr;
            if (p >= M) continue;
            int crow = scat ? scat[p] : p;
            size_t rowoff = (size_t)crow * H + nt * 128 + wn * 64;
#pragma unroll
            for (int n = 0; n < 4; ++n)
                outP[rowoff + n * 16 + l16] = f2b(acc[m][n][rr]);
        }
    }
}

// ---------------- Combine ----------------
__global__ __launch_bounds__(256) void combine_kernel(
    const short* __restrict__ outPairs, const short* __restrict__ sharedOut,
    const float* __restrict__ pairW, float* __restrict__ out)
{
    size_t gi = ((size_t)blockIdx.x * 256 + threadIdx.x) * 8;
    int t = (int)(gi >> 11);
    int h = (int)(gi & (H - 1));
    float w0 = pairW[2 * t], w1 = pairW[2 * t + 1];
    short8 p0 = *(const short8*)(outPairs + (size_t)(2 * t) * H + h);
    short8 p1 = *(const short8*)(outPairs + (size_t)(2 * t + 1) * H + h);
    short8 sh = *(const short8*)(sharedOut + gi);
    floatx4 o0, o1;
#pragma unroll
    for (int j = 0; j < 4; ++j)
        o0[j] = w0 * b2f(p0[j]) + w1 * b2f(p1[j]) + b2f(sh[j]);
#pragma unroll
    for (int j = 0; j < 4; ++j)
        o1[j] = w0 * b2f(p0[4 + j]) + w1 * b2f(p1[4 + j]) + b2f(sh[4 + j]);
    *(floatx4*)(out + gi)     = o0;
    *(floatx4*)(out + gi + 4) = o1;
}

extern "C" void kernel_launch(void* const* d_in, const int* in_sizes, int n_in,
                              void* d_out, int out_size, void* d_ws, size_t ws_size,
                              hipStream_t stream)
{
    const float* x    = (const float*)d_in[0];
    const float* rw   = (const float*)d_in[1];
    const float* bias = (const float*)d_in[2];
    const float* gw   = (const float*)d_in[3];
    const float* uw   = (const float*)d_in[4];
    const float* dw   = (const float*)d_in[5];
    const float* sgw  = (const float*)d_in[6];
    const float* suw  = (const float*)d_in[7];
    const float* sdw  = (const float*)d_in[8];
    float* out = (float*)d_out;

    char* ws = (char*)d_ws;
    size_t off = 0;
    auto alloc = [&](size_t bytes) {
        off = (off + 255) & ~(size_t)255;
        void* p = ws + off;
        off += bytes;
        return p;
    };
    int*   cnt       = (int*)  alloc(NEXP * sizeof(int));
    int*   tokList   = (int*)  alloc((size_t)NEXP * T_TOK * sizeof(int));
    int*   slotList  = (int*)  alloc((size_t)NEXP * T_TOK * sizeof(int));
    float* pairW     = (float*)alloc((size_t)2 * T_TOK * sizeof(float));
    int*   meta      = (int*)  alloc(64 * sizeof(int));
    short* xb        = (short*)alloc((size_t)T_TOK * H * sizeof(short));
    short* hiddenP   = (short*)alloc((size_t)2 * T_TOK * IMOE * sizeof(short));
    short* hiddenS   = (short*)alloc((size_t)T_TOK * ISH * sizeof(short));
    short* outPairs  = (short*)alloc((size_t)2 * T_TOK * H * sizeof(short));
    short* sharedOut = (short*)alloc((size_t)T_TOK * H * sizeof(short));
    // bf16 weight copies (~173 MB total)
    short* gwb  = (short*)alloc((size_t)NEXP * IMOE * H * sizeof(short));
    short* uwb  = (short*)alloc((size_t)NEXP * IMOE * H * sizeof(short));
    short* dwb  = (short*)alloc((size_t)NEXP * H * IMOE * sizeof(short));
    short* sgwb = (short*)alloc((size_t)ISH * H * sizeof(short));
    short* suwb = (short*)alloc((size_t)ISH * H * sizeof(short));
    short* sdwb = (short*)alloc((size_t)H * ISH * sizeof(short));
    (void)ws_size;

    hipMemsetAsync(cnt, 0, NEXP * sizeof(int), stream);

    router_kernel<<<T_TOK / 4, 256, 0, stream>>>(x, rw, bias, cnt, tokList, slotList, pairW);
    plan_kernel<<<1, 64, 0, stream>>>(cnt, meta);
    convert_kernel<<<2048, 256, 0, stream>>>(x, xb, T_TOK * H / 4);
    wconvert_kernel<<<2048, 256, 0, stream>>>(gw, uw, dw, sgw, suw, sdw,
                                              gwb, uwb, dwb, sgwb, suwb, sdwb);

    gu_gemm<<<GU_GRID, 256, 0, stream>>>(xb, gwb, uwb, sgwb, suwb,
                                         hiddenP, hiddenS, tokList, meta);
    dn_gemm<<<DN_GRID, 256, 0, stream>>>(hiddenP, hiddenS, dwb, sdwb,
                                         outPairs, sharedOut, slotList, meta);

    combine_kernel<<<(T_TOK * H / 8) / 256, 256, 0, stream>>>(outPairs, sharedOut, pairW, out);
}

// Round 5
// 622.912 us; speedup vs baseline: 1.1881x; 1.0482x over previous
//
#include <hip/hip_runtime.h>
#include <hip/hip_bf16.h>
#include <math.h>

#define H 2048
#define IMOE 1408
#define NEXP 8
#define T_TOK 2048
#define ISH 2816
#define SCALEF 2.5f

#define NT_GU_R (IMOE / 64)   // 22
#define NT_GU_S (ISH / 64)    // 44
#define NT_DN   (H / 128)     // 16
#define GU_GRID (39 * NT_GU_R + 16 * NT_GU_S)  // 1562
#define DN_GRID (39 * NT_DN + 16 * NT_DN)      // 880

typedef __attribute__((ext_vector_type(8))) short short8;
typedef __attribute__((ext_vector_type(4))) short short4v;
typedef __attribute__((ext_vector_type(4))) float floatx4;

union U8 { short8 s; unsigned u[4]; };

__device__ inline float b2f(short v) {
    unsigned int u = ((unsigned int)(unsigned short)v) << 16;
    float f; __builtin_memcpy(&f, &u, 4); return f;
}
__device__ inline short f2b(float f) {
    __hip_bfloat16 h = __float2bfloat16(f);
    short s; __builtin_memcpy(&s, &h, 2); return s;
}
__device__ __forceinline__ unsigned pkbf16(float a, float b) {
    float2 t; t.x = a; t.y = b;
    __hip_bfloat162 h2 = __float22bfloat162_rn(t);
    unsigned u; __builtin_memcpy(&u, &h2, 4); return u;
}

// async 16B/lane global->LDS; LDS dest = wave-uniform base + lane*16
__device__ __forceinline__ void async16(const short* g, short* l) {
    __builtin_amdgcn_global_load_lds(
        (const __attribute__((address_space(1))) unsigned*)g,
        (__attribute__((address_space(3))) unsigned*)l, 16, 0, 0);
}
__device__ __forceinline__ void async16f(const float* g, float* l) {
    __builtin_amdgcn_global_load_lds(
        (const __attribute__((address_space(1))) unsigned*)g,
        (__attribute__((address_space(3))) unsigned*)l, 16, 0, 0);
}

// Bijective XCD-aware remap (m204): hardware assigns blockIdx%8 -> XCD.
__device__ __forceinline__ int xcd_map(int orig, int nwg) {
    int q = nwg >> 3, r = nwg & 7;
    int x = orig & 7, s = orig >> 3;
    int base = (x < r) ? x * (q + 1) : r * (q + 1) + (x - r) * q;
    return base + s;
}

// ---------------- Router (fp32 routing, matches reference; also emits bf16 x)
__global__ __launch_bounds__(256) void router_kernel(
    const float* __restrict__ x, const float* __restrict__ rw,
    const float* __restrict__ bias,
    int* __restrict__ cnt, int* __restrict__ tokList, int* __restrict__ slotList,
    float* __restrict__ pairW, short* __restrict__ xb)
{
    const int wid  = (blockIdx.x * 256 + threadIdx.x) >> 6;
    const int lane = threadIdx.x & 63;
    if (wid >= T_TOK) return;
    const float* xr = x + (size_t)wid * H;
    short* xbrow = xb + (size_t)wid * H;

    float acc[NEXP];
#pragma unroll
    for (int e = 0; e < NEXP; ++e) acc[e] = 0.f;

#pragma unroll
    for (int c = 0; c < 8; ++c) {
        int idx = (c * 64 + lane) * 4;
        floatx4 xv = *(const floatx4*)(xr + idx);
#pragma unroll
        for (int e = 0; e < NEXP; ++e) {
            floatx4 wv = *(const floatx4*)(rw + e * H + idx);
            acc[e] += xv.x * wv.x + xv.y * wv.y + xv.z * wv.z + xv.w * wv.w;
        }
        short4v o = { f2b(xv.x), f2b(xv.y), f2b(xv.z), f2b(xv.w) };
        *(short4v*)(xbrow + idx) = o;       // fused x fp32->bf16 convert
    }
#pragma unroll
    for (int e = 0; e < NEXP; ++e)
        for (int off = 32; off; off >>= 1)
            acc[e] += __shfl_xor(acc[e], off, 64);

    if (lane == 0) {
        float s[NEXP], sfc[NEXP];
#pragma unroll
        for (int e = 0; e < NEXP; ++e) {
            s[e]   = 1.0f / (1.0f + expf(-acc[e]));
            sfc[e] = s[e] + bias[e];
        }
        float gs[4];
#pragma unroll
        for (int g = 0; g < 4; ++g) gs[g] = sfc[2 * g] + sfc[2 * g + 1];
        int g1 = 0;
        for (int g = 1; g < 4; ++g) if (gs[g] > gs[g1]) g1 = g;
        int g2 = -1;
        for (int g = 0; g < 4; ++g) {
            if (g == g1) continue;
            if (g2 < 0 || gs[g] > gs[g2]) g2 = g;
        }
        float msk[NEXP];
#pragma unroll
        for (int e = 0; e < NEXP; ++e) {
            int g = e >> 1;
            msk[e] = (g == g1 || g == g2) ? sfc[e] : 0.0f;
        }
        int e1 = 0;
        for (int e = 1; e < NEXP; ++e) if (msk[e] > msk[e1]) e1 = e;
        int e2 = -1;
        for (int e = 0; e < NEXP; ++e) {
            if (e == e1) continue;
            if (e2 < 0 || msk[e] > msk[e2]) e2 = e;
        }
        float w1 = s[e1], w2 = s[e2];
        float inv = SCALEF / (w1 + w2 + 1e-20f);
        w1 *= inv; w2 *= inv;
        int p1 = atomicAdd(&cnt[e1], 1);
        tokList[e1 * T_TOK + p1]  = wid;
        slotList[e1 * T_TOK + p1] = 2 * wid;
        pairW[2 * wid] = w1;
        int p2 = atomicAdd(&cnt[e2], 1);
        tokList[e2 * T_TOK + p2]  = wid;
        slotList[e2 * T_TOK + p2] = 2 * wid + 1;
        pairW[2 * wid + 1] = w2;
    }
}

// ---------------- Plan ----------------
// meta[0..8]  : M per entry (entry 8 = shared, 2048)
// meta[9..17] : compact row base
// meta[20..29]: gate/up item starts
// meta[32..41]: down item starts (meta[40]=routed end)
__global__ void plan_kernel(const int* __restrict__ cnt, int* __restrict__ meta)
{
    if (blockIdx.x != 0 || threadIdx.x != 0) return;
    int base = 0, gu = 0, dn = 0;
    meta[20] = 0; meta[32] = 0;
    for (int e = 0; e < NEXP; ++e) {
        int M = cnt[e];
        meta[e] = M;
        meta[9 + e] = base;
        base += M;
        int MT = (M + 127) >> 7;
        gu += MT * NT_GU_R;
        dn += MT * NT_DN;
        meta[21 + e] = gu;
        meta[33 + e] = dn;
    }
    meta[8]  = T_TOK;   // shared M
    meta[17] = 0;       // shared base (separate buffer)
    meta[29] = gu + 16 * NT_GU_S;
    meta[41] = dn + 16 * NT_DN;
}

// ---------------- Fused gate+up grouped GEMM ----------------
// BM=128, BN=64 per matrix, BK=64, K=2048. A bf16 via async16; B staged as
// RAW FP32 via async16 (no wconvert pass, no reg round-trip), converted to
// bf16 on the LDS->reg read path (2x ds_read_b128 + 4 cvt_pk per frag).
// fp32 tile swizzle: 16 chunks/row, phys = chunk ^ (row&15) -> each bank hit
// exactly 8x per wave-read (balanced, 0 conflicts). Single-buffer 2-barrier
// (round-4 dbuf measured NULL). Epilogue: silu(g)*u -> compact hidden.
__global__ __launch_bounds__(256) void gu_gemm(
    const short* __restrict__ xb,
    const float* __restrict__ gw, const float* __restrict__ uw,
    const float* __restrict__ sgw, const float* __restrict__ suw,
    short* __restrict__ hiddenP, short* __restrict__ hiddenS,
    const int* __restrict__ tokList, const int* __restrict__ meta)
{
    const int total = meta[29];
    if (blockIdx.x >= total) return;
    const int idx = xcd_map(blockIdx.x, total);
    int e = 0;
    while (e < 8 && idx >= meta[21 + e]) ++e;

    int M, NT, Nout, rowBase;
    const float *b1, *b2;
    const int* gat;
    short* outP;
    if (e < 8) {
        M = meta[e]; NT = NT_GU_R; Nout = IMOE; rowBase = meta[9 + e];
        b1 = gw + (size_t)e * IMOE * H;
        b2 = uw + (size_t)e * IMOE * H;
        gat = tokList + e * T_TOK;
        outP = hiddenP;
    } else {
        M = T_TOK; NT = NT_GU_S; Nout = ISH; rowBase = 0;
        b1 = sgw; b2 = suw; gat = nullptr; outP = hiddenS;
    }
    const int MT = (M + 127) >> 7;
    const int local = idx - meta[20 + e];
    const int mt = local % MT;          // mt-minor: adjacent blocks share weight tile
    const int nt = local / MT;

    __shared__ short As[128 * 64];      // bf16, 16 KB
    __shared__ float Bg[64 * 64];       // fp32, 16 KB
    __shared__ float Bu[64 * 64];       // fp32, 16 KB

    const int tid  = threadIdx.x;
    const int w    = tid >> 6;
    const int lane = tid & 63;
    const int quad = lane >> 4;
    const int l16  = lane & 15;
    const int wm = w >> 1, wn = w & 1;

    // A staging: 8 bf16-rows (128 B each) per inst, pre-swizzled source chunk
    const int r8 = lane >> 3;
    const int csA = (lane & 7) ^ r8;
    const short* aSrc[4];
    short* ldsA[4];
#pragma unroll
    for (int i = 0; i < 4; ++i) {
        int r = w * 32 + i * 8 + r8;
        int p = mt * 128 + r;
        int pos = p < M ? p : (M - 1);
        int arow = gat ? gat[pos] : pos;
        aSrc[i] = xb + (size_t)arow * H + csA * 8;
        ldsA[i] = As + (w * 32 + i * 8) * 64;
    }

    // B staging (fp32): 4 rows (256 B each) per inst; source chunk pre-swizzled
    const int br4 = lane >> 4;          // row within 4-row group
    const int bc  = lane & 15;          // phys 16B chunk
    const float* bgSrc[4];
    const float* buSrc[4];
    float* ldsBg[4];
    float* ldsBu[4];
#pragma unroll
    for (int i = 0; i < 4; ++i) {
        int rb = w * 16 + i * 4;
        int row = rb + br4;
        int sc = bc ^ (row & 15);
        bgSrc[i] = b1 + (size_t)(nt * 64 + row) * H + sc * 4;
        buSrc[i] = b2 + (size_t)(nt * 64 + row) * H + sc * 4;
        ldsBg[i] = Bg + rb * 64;
        ldsBu[i] = Bu + rb * 64;
    }

    floatx4 accg[4][2] = {};
    floatx4 accu[4][2] = {};

    for (int k0 = 0; k0 < H; k0 += 64) {
#pragma unroll
        for (int i = 0; i < 4; ++i) async16(aSrc[i] + k0, ldsA[i]);
#pragma unroll
        for (int i = 0; i < 4; ++i) async16f(bgSrc[i] + k0, ldsBg[i]);
#pragma unroll
        for (int i = 0; i < 4; ++i) async16f(buSrc[i] + k0, ldsBu[i]);
        __syncthreads();

        const int sw = l16 & 7;
        short8 af[4], bgf[2], buf[2];
#pragma unroll
        for (int kk2 = 0; kk2 < 2; ++kk2) {
            const int c = kk2 * 4 + quad;
#pragma unroll
            for (int m = 0; m < 4; ++m)
                af[m] = *(const short8*)(As + (wm * 64 + m * 16 + l16) * 64 + (c ^ sw) * 8);
#pragma unroll
            for (int n = 0; n < 2; ++n) {
                int rg = wn * 32 + n * 16 + l16;
                const float* pg = Bg + rg * 64;
                const float* pu = Bu + rg * 64;
                int j0 = ((2 * c)     ^ (rg & 15)) * 4;
                int j1 = ((2 * c + 1) ^ (rg & 15)) * 4;
                floatx4 g0 = *(const floatx4*)(pg + j0);
                floatx4 g1 = *(const floatx4*)(pg + j1);
                floatx4 u0 = *(const floatx4*)(pu + j0);
                floatx4 u1 = *(const floatx4*)(pu + j1);
                U8 tg, tu;
                tg.u[0] = pkbf16(g0.x, g0.y); tg.u[1] = pkbf16(g0.z, g0.w);
                tg.u[2] = pkbf16(g1.x, g1.y); tg.u[3] = pkbf16(g1.z, g1.w);
                tu.u[0] = pkbf16(u0.x, u0.y); tu.u[1] = pkbf16(u0.z, u0.w);
                tu.u[2] = pkbf16(u1.x, u1.y); tu.u[3] = pkbf16(u1.z, u1.w);
                bgf[n] = tg.s;
                buf[n] = tu.s;
            }
#pragma unroll
            for (int m = 0; m < 4; ++m)
#pragma unroll
                for (int n = 0; n < 2; ++n) {
                    accg[m][n] = __builtin_amdgcn_mfma_f32_16x16x32_bf16(af[m], bgf[n], accg[m][n], 0, 0, 0);
                    accu[m][n] = __builtin_amdgcn_mfma_f32_16x16x32_bf16(af[m], buf[n], accu[m][n], 0, 0, 0);
                }
        }
        __syncthreads();
    }

    // epilogue: silu(g)*u -> compact hidden. C/D layout: col=l16, row=quad*4+rr
#pragma unroll
    for (int m = 0; m < 4; ++m) {
#pragma unroll
        for (int rr = 0; rr < 4; ++rr) {
            int lr = wm * 64 + m * 16 + quad * 4 + rr;
            int p = mt * 128 + lr;
            if (p >= M) continue;
            size_t rowoff = (size_t)(rowBase + p) * Nout + nt * 64 + wn * 32;
#pragma unroll
            for (int n = 0; n < 2; ++n) {
                float g = accg[m][n][rr];
                float u = accu[m][n][rr];
                outP[rowoff + n * 16 + l16] = f2b(g / (1.0f + __expf(-g)) * u);
            }
        }
    }
}

// ---------------- Down grouped GEMM ----------------
// BM=128, BN=128, BK=64, K = 1408 (routed) / 2816 (shared). A bf16 hidden;
// B raw fp32 via async16f with 16-chunk XOR swizzle, cvt on read path.
// Per-range XCD remap keeps L2 locality AND per-XCD balance.
__global__ __launch_bounds__(256) void dn_gemm(
    const short* __restrict__ hiddenP, const short* __restrict__ hiddenS,
    const float* __restrict__ dw, const float* __restrict__ sdw,
    short* __restrict__ outPairs, short* __restrict__ sharedOut,
    const int* __restrict__ slotList, const int* __restrict__ meta)
{
    const int total = meta[41];
    if (blockIdx.x >= total) return;
    const int rtot = meta[40];
    int idx;
    if (blockIdx.x < rtot) idx = xcd_map(blockIdx.x, rtot);
    else                   idx = rtot + xcd_map(blockIdx.x - rtot, total - rtot);
    int e = 0;
    while (e < 8 && idx >= meta[33 + e]) ++e;

    int M, K, rowBase;
    const float* bp;
    const short* Abase;
    const int* scat;
    short* outP;
    if (e < 8) {
        M = meta[e]; K = IMOE; rowBase = meta[9 + e];
        bp = dw + (size_t)e * H * IMOE;
        Abase = hiddenP; scat = slotList + e * T_TOK; outP = outPairs;
    } else {
        M = T_TOK; K = ISH; rowBase = 0;
        bp = sdw; Abase = hiddenS; scat = nullptr; outP = sharedOut;
    }
    const int MT = (M + 127) >> 7;
    const int local = idx - meta[32 + e];
    const int mt = local % MT;
    const int nt = local / MT;

    __shared__ short As[128 * 64];      // bf16, 16 KB
    __shared__ float Bf[128 * 64];      // fp32, 32 KB

    const int tid  = threadIdx.x;
    const int w    = tid >> 6;
    const int lane = tid & 63;
    const int quad = lane >> 4;
    const int l16  = lane & 15;
    const int wm = w >> 1, wn = w & 1;

    const int r8 = lane >> 3;
    const int csA = (lane & 7) ^ r8;
    const short* aSrc[4];
    short* ldsA[4];
#pragma unroll
    for (int i = 0; i < 4; ++i) {
        int r = w * 32 + i * 8 + r8;
        int p = mt * 128 + r;
        int pos = p < M ? p : (M - 1);
        aSrc[i] = Abase + (size_t)(rowBase + pos) * K + csA * 8;
        ldsA[i] = As + (w * 32 + i * 8) * 64;
    }

    const int br4 = lane >> 4;
    const int bc  = lane & 15;
    const float* bSrc[8];
    float* ldsB[8];
#pragma unroll
    for (int i = 0; i < 8; ++i) {
        int rb = w * 32 + i * 4;
        int row = rb + br4;
        int sc = bc ^ (row & 15);
        bSrc[i] = bp + (size_t)(nt * 128 + row) * K + sc * 4;
        ldsB[i] = Bf + rb * 64;
    }

    floatx4 acc[4][4] = {};

    const int kIters = K >> 6;
    for (int kt = 0; kt < kIters; ++kt) {
        const int k0 = kt << 6;
#pragma unroll
        for (int i = 0; i < 4; ++i) async16(aSrc[i] + k0, ldsA[i]);
#pragma unroll
        for (int i = 0; i < 8; ++i) async16f(bSrc[i] + k0, ldsB[i]);
        __syncthreads();

        const int sw = l16 & 7;
        short8 af[4], bf[4];
#pragma unroll
        for (int kk2 = 0; kk2 < 2; ++kk2) {
            const int c = kk2 * 4 + quad;
#pragma unroll
            for (int m = 0; m < 4; ++m)
                af[m] = *(const short8*)(As + (wm * 64 + m * 16 + l16) * 64 + (c ^ sw) * 8);
#pragma unroll
            for (int n = 0; n < 4; ++n) {
                int rb2 = wn * 64 + n * 16 + l16;
                const float* pb = Bf + rb2 * 64;
                floatx4 b0 = *(const floatx4*)(pb + (((2 * c)     ^ (rb2 & 15)) * 4));
                floatx4 b1 = *(const floatx4*)(pb + (((2 * c + 1) ^ (rb2 & 15)) * 4));
                U8 t;
                t.u[0] = pkbf16(b0.x, b0.y); t.u[1] = pkbf16(b0.z, b0.w);
                t.u[2] = pkbf16(b1.x, b1.y); t.u[3] = pkbf16(b1.z, b1.w);
                bf[n] = t.s;
            }
#pragma unroll
            for (int m = 0; m < 4; ++m)
#pragma unroll
                for (int n = 0; n < 4; ++n)
                    acc[m][n] = __builtin_amdgcn_mfma_f32_16x16x32_bf16(af[m], bf[n], acc[m][n], 0, 0, 0);
        }
        __syncthreads();
    }

#pragma unroll
    for (int m = 0; m < 4; ++m) {
#pragma unroll
        for (int rr = 0; rr < 4; ++rr) {
            int lr = wm * 64 + m * 16 + quad * 4 + rr;
            int p = mt * 128 + lr;
            if (p >= M) continue;
            int crow = scat ? scat[p] : p;
            size_t rowoff = (size_t)crow * H + nt * 128 + wn * 64;
#pragma unroll
            for (int n = 0; n < 4; ++n)
                outP[rowoff + n * 16 + l16] = f2b(acc[m][n][rr]);
        }
    }
}

// ---------------- Combine ----------------
__global__ __launch_bounds__(256) void combine_kernel(
    const short* __restrict__ outPairs, const short* __restrict__ sharedOut,
    const float* __restrict__ pairW, float* __restrict__ out)
{
    size_t gi = ((size_t)blockIdx.x * 256 + threadIdx.x) * 8;
    int t = (int)(gi >> 11);
    int h = (int)(gi & (H - 1));
    float w0 = pairW[2 * t], w1 = pairW[2 * t + 1];
    short8 p0 = *(const short8*)(outPairs + (size_t)(2 * t) * H + h);
    short8 p1 = *(const short8*)(outPairs + (size_t)(2 * t + 1) * H + h);
    short8 sh = *(const short8*)(sharedOut + gi);
    floatx4 o0, o1;
#pragma unroll
    for (int j = 0; j < 4; ++j)
        o0[j] = w0 * b2f(p0[j]) + w1 * b2f(p1[j]) + b2f(sh[j]);
#pragma unroll
    for (int j = 0; j < 4; ++j)
        o1[j] = w0 * b2f(p0[4 + j]) + w1 * b2f(p1[4 + j]) + b2f(sh[4 + j]);
    *(floatx4*)(out + gi)     = o0;
    *(floatx4*)(out + gi + 4) = o1;
}

extern "C" void kernel_launch(void* const* d_in, const int* in_sizes, int n_in,
                              void* d_out, int out_size, void* d_ws, size_t ws_size,
                              hipStream_t stream)
{
    const float* x    = (const float*)d_in[0];
    const float* rw   = (const float*)d_in[1];
    const float* bias = (const float*)d_in[2];
    const float* gw   = (const float*)d_in[3];
    const float* uw   = (const float*)d_in[4];
    const float* dw   = (const float*)d_in[5];
    const float* sgw  = (const float*)d_in[6];
    const float* suw  = (const float*)d_in[7];
    const float* sdw  = (const float*)d_in[8];
    float* out = (float*)d_out;

    char* ws = (char*)d_ws;
    size_t off = 0;
    auto alloc = [&](size_t bytes) {
        off = (off + 255) & ~(size_t)255;
        void* p = ws + off;
        off += bytes;
        return p;
    };
    int*   cnt       = (int*)  alloc(NEXP * sizeof(int));
    int*   tokList   = (int*)  alloc((size_t)NEXP * T_TOK * sizeof(int));
    int*   slotList  = (int*)  alloc((size_t)NEXP * T_TOK * sizeof(int));
    float* pairW     = (float*)alloc((size_t)2 * T_TOK * sizeof(float));
    int*   meta      = (int*)  alloc(64 * sizeof(int));
    short* xb        = (short*)alloc((size_t)T_TOK * H * sizeof(short));
    short* hiddenP   = (short*)alloc((size_t)2 * T_TOK * IMOE * sizeof(short));
    short* hiddenS   = (short*)alloc((size_t)T_TOK * ISH * sizeof(short));
    short* outPairs  = (short*)alloc((size_t)2 * T_TOK * H * sizeof(short));
    short* sharedOut = (short*)alloc((size_t)T_TOK * H * sizeof(short));
    (void)ws_size;

    hipMemsetAsync(cnt, 0, NEXP * sizeof(int), stream);

    router_kernel<<<T_TOK / 4, 256, 0, stream>>>(x, rw, bias, cnt, tokList, slotList, pairW, xb);
    plan_kernel<<<1, 64, 0, stream>>>(cnt, meta);

    gu_gemm<<<GU_GRID, 256, 0, stream>>>(xb, gw, uw, sgw, suw,
                                         hiddenP, hiddenS, tokList, meta);
    dn_gemm<<<DN_GRID, 256, 0, stream>>>(hiddenP, hiddenS, dw, sdw,
                                         outPairs, sharedOut, slotList, meta);

    combine_kernel<<<(T_TOK * H / 8) / 256, 256, 0, stream>>>(outPairs, sharedOut, pairW, out);
}